// Round 1
// baseline (415.910 us; speedup 1.0000x reference)
//
#include <hip/hip_runtime.h>
#include <math.h>

// ---------------------------------------------------------------------------
// IterNorm: X (64,256,56,56) fp32, groups of 64 channels (g=4).
// Pass 1 (k_gram):  G[g] = X_g X_g^T (64x64) + per-channel sums, fused.
// Pass 2 (k_solve): Sigma = G/m - mu mu^T + eps I; rTr = 1/tr(Sigma);
//                   Newton-Schulz x5 on Sigma*rTr; fold weight/bias/mean into
//                   wmW[c][e] = weight[c]*sqrt(rTr)*P[c][e],
//                   beta[c]   = bias[c] - weight[c]*(wm . mu)[c].
// Pass 3 (k_apply): out[c][m] = sum_e wmW[c][e]*X[e][m] + beta[c].
// ---------------------------------------------------------------------------

#define EPS_F 1e-5f

constexpr int Bb  = 64;
constexpr int Cc  = 256;
constexpr int HWc = 3136;                 // 56*56
constexpr int NCc = 64;                   // channels per group
constexpr int CHW = Cc * HWc;             // 802816
constexpr float Mf = 200704.0f;           // 64*3136
constexpr int TILES_PER_G = Bb * (HWc / 64); // 64*49 = 3136

// workspace layout (float offsets)
constexpr int WS_G    = 0;      // 4*64*64 = 16384 floats (Gram accumulators)
constexpr int WS_SUM  = 16384;  // 256 floats (channel sums)
constexpr int WS_WM   = 16640;  // 16384 floats (folded whitening matrices)
constexpr int WS_BETA = 33024;  // 256 floats (folded bias)
constexpr int WS_ZERO_FLOATS = 16640; // region that must be zeroed per launch

// ---------------------------------------------------------------------------
// Kernel 1: Gram matrix + channel sums.
// grid (128, 4) x 256 threads. Each block: subset of 64-wide m-tiles for one group.
// ---------------------------------------------------------------------------
extern "C" __global__ __launch_bounds__(256)
void k_gram(const float* __restrict__ X, float* __restrict__ ws) {
    __shared__ float tile[64][65];        // [channel][m], pad -> stride 65 (conflict-free)
    const int g   = blockIdx.y;
    const int tid = threadIdx.x;
    const int c_ld = tid >> 2;            // 0..63 channel this thread loads
    const int ms   = (tid & 3) << 4;      // 0,16,32,48 m-offset this thread loads
    const int bi   = tid >> 4;            // 0..15 row-block
    const int bj   = tid & 15;            // 0..15 col-block
    float acc[4][4] = {};
    float csum = 0.0f;

    const float* Xg = X + (size_t)g * NCc * HWc;

    for (int t = blockIdx.x; t < TILES_PER_G; t += gridDim.x) {
        const int b   = t / 49;
        const int hw0 = (t % 49) << 6;
        const float* p = Xg + (size_t)b * CHW + (size_t)c_ld * HWc + hw0 + ms;
        const float4 v0 = *(const float4*)(p + 0);
        const float4 v1 = *(const float4*)(p + 4);
        const float4 v2 = *(const float4*)(p + 8);
        const float4 v3 = *(const float4*)(p + 12);
        csum += (v0.x + v0.y + v0.z + v0.w) + (v1.x + v1.y + v1.z + v1.w)
              + (v2.x + v2.y + v2.z + v2.w) + (v3.x + v3.y + v3.z + v3.w);

        __syncthreads();                  // previous tile fully consumed
        float* tr = &tile[c_ld][ms];
        tr[0]=v0.x;  tr[1]=v0.y;  tr[2]=v0.z;  tr[3]=v0.w;
        tr[4]=v1.x;  tr[5]=v1.y;  tr[6]=v1.z;  tr[7]=v1.w;
        tr[8]=v2.x;  tr[9]=v2.y;  tr[10]=v2.z; tr[11]=v2.w;
        tr[12]=v3.x; tr[13]=v3.y; tr[14]=v3.z; tr[15]=v3.w;
        __syncthreads();

        #pragma unroll 8
        for (int k = 0; k < 64; ++k) {
            const float a0 = tile[4*bi+0][k];
            const float a1 = tile[4*bi+1][k];
            const float a2 = tile[4*bi+2][k];
            const float a3 = tile[4*bi+3][k];
            const float b0 = tile[4*bj+0][k];
            const float b1 = tile[4*bj+1][k];
            const float b2 = tile[4*bj+2][k];
            const float b3 = tile[4*bj+3][k];
            acc[0][0] += a0*b0; acc[0][1] += a0*b1; acc[0][2] += a0*b2; acc[0][3] += a0*b3;
            acc[1][0] += a1*b0; acc[1][1] += a1*b1; acc[1][2] += a1*b2; acc[1][3] += a1*b3;
            acc[2][0] += a2*b0; acc[2][1] += a2*b1; acc[2][2] += a2*b2; acc[2][3] += a2*b3;
            acc[3][0] += a3*b0; acc[3][1] += a3*b1; acc[3][2] += a3*b2; acc[3][3] += a3*b3;
        }
    }

    // channel-sum reduction: 4 lanes share a channel (tid>>2)
    csum += __shfl_down(csum, 1, 4);
    csum += __shfl_down(csum, 2, 4);
    if ((tid & 3) == 0) atomicAdd(&ws[WS_SUM + g*64 + c_ld], csum);

    float* Gp = ws + WS_G + g * 4096;
    #pragma unroll
    for (int i = 0; i < 4; ++i)
        #pragma unroll
        for (int j = 0; j < 4; ++j)
            atomicAdd(&Gp[(4*bi + i) * 64 + (4*bj + j)], acc[i][j]);
}

// ---------------------------------------------------------------------------
// Kernel 2: build Sigma, Newton-Schulz, fold weight/bias. 4 blocks x 1024 thr.
// ---------------------------------------------------------------------------
__device__ __forceinline__
void mm64(float (*Cm)[65], float (*Am)[65], float (*Bm)[65], int r, int c0) {
    // C = A * B for 64x64 in LDS; safe when C aliases A or B (regs -> sync -> write).
    float s0 = 0.f, s1 = 0.f, s2 = 0.f, s3 = 0.f;
    #pragma unroll 8
    for (int k = 0; k < 64; ++k) {
        const float a = Am[r][k];
        s0 += a * Bm[k][c0+0];
        s1 += a * Bm[k][c0+1];
        s2 += a * Bm[k][c0+2];
        s3 += a * Bm[k][c0+3];
    }
    __syncthreads();
    Cm[r][c0+0] = s0; Cm[r][c0+1] = s1; Cm[r][c0+2] = s2; Cm[r][c0+3] = s3;
    __syncthreads();
}

extern "C" __global__ __launch_bounds__(1024)
void k_solve(const float* __restrict__ weight, const float* __restrict__ bias,
             float* __restrict__ ws) {
    __shared__ float S[64][65];
    __shared__ float P[64][65];
    __shared__ float T1[64][65];
    __shared__ float mean_s[64];
    __shared__ float red;

    const int g   = blockIdx.x;
    const int tid = threadIdx.x;
    const int r   = tid >> 4;            // 0..63
    const int c0  = (tid & 15) << 2;     // 0,4,...,60

    const float* Gp = ws + WS_G + g * 4096;
    if (tid < 64) mean_s[tid] = ws[WS_SUM + g*64 + tid] * (1.0f / Mf);
    __syncthreads();

    #pragma unroll
    for (int j = 0; j < 4; ++j) {
        const int c = c0 + j;
        float v = Gp[r*64 + c] * (1.0f / Mf) - mean_s[r] * mean_s[c];
        if (r == c) v += EPS_F;
        S[r][c] = v;
        P[r][c] = (r == c) ? 1.0f : 0.0f;
    }
    __syncthreads();

    if (tid == 0) {
        float tr = 0.f;
        for (int i = 0; i < 64; ++i) tr += S[i][i];
        red = 1.0f / tr;
    }
    __syncthreads();
    const float rtr = red;
    #pragma unroll
    for (int j = 0; j < 4; ++j) S[r][c0+j] *= rtr;
    __syncthreads();

    for (int it = 0; it < 5; ++it) {
        mm64(T1, P,  P, r, c0);          // T1 = P^2
        mm64(T1, T1, P, r, c0);          // T1 = P^3
        mm64(T1, T1, S, r, c0);          // T1 = P^3 * Sigma_N
        #pragma unroll
        for (int j = 0; j < 4; ++j)
            P[r][c0+j] = 1.5f * P[r][c0+j] - 0.5f * T1[r][c0+j];
        __syncthreads();
    }

    const float srtr = sqrtf(rtr);
    const float wrow = weight[g*64 + r];
    float* Wp = ws + WS_WM + g * 4096;
    float part = 0.0f;
    #pragma unroll
    for (int j = 0; j < 4; ++j) {
        const int e = c0 + j;
        const float wm = P[r][e] * srtr;  // whitening matrix entry
        Wp[r*64 + e] = wm * wrow;         // fold weight
        part += wm * mean_s[e];
    }
    T1[r][tid & 15] = part;
    __syncthreads();
    if (tid < 64) {
        float dot = 0.f;
        for (int q = 0; q < 16; ++q) dot += T1[tid][q];
        ws[WS_BETA + g*64 + tid] = bias[g*64 + tid] - weight[g*64 + tid] * dot;
    }
}

// ---------------------------------------------------------------------------
// Kernel 3: apply whitening. out = wmW * X + beta. grid (128,4) x 256 thr.
// ---------------------------------------------------------------------------
extern "C" __global__ __launch_bounds__(256)
void k_apply(const float* __restrict__ X, const float* __restrict__ ws,
             float* __restrict__ out) {
    __shared__ float tile[64][65];
    __shared__ float wm_s[64][65];
    __shared__ float beta_s[64];

    const int g   = blockIdx.y;
    const int tid = threadIdx.x;

    const float* Wp = ws + WS_WM + g * 4096;
    for (int i = tid; i < 4096; i += 256) wm_s[i >> 6][i & 63] = Wp[i];
    if (tid < 64) beta_s[tid] = ws[WS_BETA + g*64 + tid];

    const int c_ld = tid >> 2;
    const int ms   = (tid & 3) << 4;
    const int bi   = tid >> 4;
    const int bj   = tid & 15;
    __syncthreads();

    for (int t = blockIdx.x; t < TILES_PER_G; t += gridDim.x) {
        const int b   = t / 49;
        const int hw0 = (t % 49) << 6;
        const size_t base = (size_t)b * CHW + (size_t)(g*64) * HWc + hw0;
        const float* p = X + base + (size_t)c_ld * HWc + ms;
        const float4 v0 = *(const float4*)(p + 0);
        const float4 v1 = *(const float4*)(p + 4);
        const float4 v2 = *(const float4*)(p + 8);
        const float4 v3 = *(const float4*)(p + 12);

        __syncthreads();
        float* tr = &tile[c_ld][ms];
        tr[0]=v0.x;  tr[1]=v0.y;  tr[2]=v0.z;  tr[3]=v0.w;
        tr[4]=v1.x;  tr[5]=v1.y;  tr[6]=v1.z;  tr[7]=v1.w;
        tr[8]=v2.x;  tr[9]=v2.y;  tr[10]=v2.z; tr[11]=v2.w;
        tr[12]=v3.x; tr[13]=v3.y; tr[14]=v3.z; tr[15]=v3.w;
        __syncthreads();

        float acc[4][4] = {};
        #pragma unroll 8
        for (int k = 0; k < 64; ++k) {
            const float a0 = wm_s[4*bi+0][k];
            const float a1 = wm_s[4*bi+1][k];
            const float a2 = wm_s[4*bi+2][k];
            const float a3 = wm_s[4*bi+3][k];
            const float t0 = tile[k][4*bj+0];
            const float t1 = tile[k][4*bj+1];
            const float t2 = tile[k][4*bj+2];
            const float t3 = tile[k][4*bj+3];
            acc[0][0] += a0*t0; acc[0][1] += a0*t1; acc[0][2] += a0*t2; acc[0][3] += a0*t3;
            acc[1][0] += a1*t0; acc[1][1] += a1*t1; acc[1][2] += a1*t2; acc[1][3] += a1*t3;
            acc[2][0] += a2*t0; acc[2][1] += a2*t1; acc[2][2] += a2*t2; acc[2][3] += a2*t3;
            acc[3][0] += a3*t0; acc[3][1] += a3*t1; acc[3][2] += a3*t2; acc[3][3] += a3*t3;
        }

        #pragma unroll
        for (int i = 0; i < 4; ++i) {
            const int c = 4*bi + i;
            const float bta = beta_s[c];
            float4 o;
            o.x = acc[i][0] + bta;
            o.y = acc[i][1] + bta;
            o.z = acc[i][2] + bta;
            o.w = acc[i][3] + bta;
            *(float4*)(out + base + (size_t)c * HWc + (4*bj)) = o;
        }
    }
}

// ---------------------------------------------------------------------------
extern "C" void kernel_launch(void* const* d_in, const int* in_sizes, int n_in,
                              void* d_out, int out_size, void* d_ws, size_t ws_size,
                              hipStream_t stream) {
    const float* X      = (const float*)d_in[0];
    const float* weight = (const float*)d_in[1];
    const float* bias   = (const float*)d_in[2];
    float* out = (float*)d_out;
    float* ws  = (float*)d_ws;

    // zero Gram + sums accumulators (atomics accumulate into them each launch)
    hipMemsetAsync(ws, 0, (size_t)WS_ZERO_FLOATS * sizeof(float), stream);

    hipLaunchKernelGGL(k_gram,  dim3(128, 4), dim3(256),  0, stream, X, ws);
    hipLaunchKernelGGL(k_solve, dim3(4),      dim3(1024), 0, stream, weight, bias, ws);
    hipLaunchKernelGGL(k_apply, dim3(128, 4), dim3(256),  0, stream, X, ws, out);
}

// Round 2
// 327.423 us; speedup vs baseline: 1.2703x; 1.2703x over previous
//
#include <hip/hip_runtime.h>
#include <math.h>

// ---------------------------------------------------------------------------
// IterNorm (64,256,56,56) fp32, g=4 groups of 64 channels.
//  k_gram : G = X_g X_g^T + channel sums (global_load_lds staged, 4x4 microtile)
//  k_solve: Sigma=G/m-mu mu^T+eps I; Newton-Schulz x5; fold weight/bias/mean
//  k_apply: out = (w*wm) X + beta   (global_load_lds staged, 4x4 microtile)
// ---------------------------------------------------------------------------

#define EPS_F 1e-5f

typedef float f32x4 __attribute__((ext_vector_type(4)));

constexpr int Bb  = 64;
constexpr int Cc  = 256;
constexpr int HWc = 3136;                 // 56*56
constexpr int CHW = Cc * HWc;             // 802816
constexpr float Mf = 200704.0f;           // 64*3136
constexpr int NT  = 3136;                 // m-tiles per group (64 * 49)
constexpr int GX  = 196;                  // grid.x -> exactly 16 tiles/block

// workspace layout (float offsets)
constexpr int WS_G    = 0;       // 4*64*64 Gram accumulators
constexpr int WS_SUM  = 16384;   // 256 channel sums
constexpr int WS_WM   = 16640;   // 4*64*64 folded whitening matrices
constexpr int WS_BETA = 33024;   // 256 folded bias
constexpr int WS_ZERO_FLOATS = 16640;

__device__ __forceinline__ void gload_lds16(const float* g, float* l) {
    __builtin_amdgcn_global_load_lds(
        (const __attribute__((address_space(1))) void*)(g),
        (__attribute__((address_space(3))) void*)(l),
        16, 0, 0);
}

__device__ __forceinline__ float dot4(f32x4 a, f32x4 b, float s) {
    s = fmaf(a.x, b.x, s); s = fmaf(a.y, b.y, s);
    s = fmaf(a.z, b.z, s); s = fmaf(a.w, b.w, s);
    return s;
}

__device__ __forceinline__ f32x4 fma4(float a, f32x4 b, f32x4 c) {
    c.x = fmaf(a, b.x, c.x); c.y = fmaf(a, b.y, c.y);
    c.z = fmaf(a, b.z, c.z); c.w = fmaf(a, b.w, c.w);
    return c;
}

// ---------------------------------------------------------------------------
// Kernel 1: Gram + channel sums. grid (196,4) x 256.
// LDS tile: [64 rows][68 floats] (stride 272B: 16B-aligned, rows spread over
// 8 bank groups -> 2-way max on column-slice reads = free).
// Staged via 17 global_load_lds_dwordx4 per tile (granule 1088 = 17*64;
// 1/17 granules land in dead pad).
// ---------------------------------------------------------------------------
extern "C" __global__ __launch_bounds__(256)
void k_gram(const float* __restrict__ X, float* __restrict__ ws) {
    __shared__ __align__(16) float tile[2][64 * 68];
    const int g    = blockIdx.y;
    const int tid  = threadIdx.x;
    const int lane = tid & 63;
    const int w    = tid >> 6;
    const float* Xg = X + (size_t)g * 64 * HWc;

    // granule mapping (loop-invariant)
    int goff[5], lbase[5];
    #pragma unroll
    for (int q = 0; q < 5; ++q) {
        const int inst = (q < 4) ? (w * 4 + q) : 16;
        const int gr   = inst * 64 + lane;
        const int row  = gr / 17;
        int slot = gr - row * 17;
        if (slot > 15) slot = 15;            // pad granule: load harmless dup
        goff[q]  = row * HWc + slot * 4;     // per-lane global float offset
        lbase[q] = inst * 256;               // wave-uniform LDS float base
    }
    const int nq = (w == 0) ? 5 : 4;

    auto issue = [&](int t, int b) {
        const int bb  = t / 49;
        const int hw0 = (t - bb * 49) << 6;
        const float* src = Xg + (size_t)bb * CHW + hw0;
        float* dst = tile[b];
        #pragma unroll
        for (int q = 0; q < 5; ++q)
            if (q < nq) gload_lds16(src + goff[q], dst + lbase[q]);
    };

    const int ri = tid >> 4;   // 0..15 (a-row group; 4 distinct rows/wave -> broadcast)
    const int rj = tid & 15;   // 0..15 (b-row group; 16 rows -> 2-way w/ stride 68)
    const int ao0 = (ri     ) * 68, ao1 = (ri + 16) * 68,
              ao2 = (ri + 32) * 68, ao3 = (ri + 48) * 68;
    const int bo0 = (rj     ) * 68, bo1 = (rj + 16) * 68,
              bo2 = (rj + 32) * 68, bo3 = (rj + 48) * 68;
    const int soff = (tid >> 2) * 68 + (tid & 3) * 16;

    float acc[4][4] = {};
    float csum = 0.0f;

    int t = blockIdx.x;
    issue(t, 0);
    __syncthreads();                       // drains vmcnt -> tile 0 ready
    int buf = 0;
    for (; t < NT; t += GX) {
        const int tn = t + GX;
        if (tn < NT) issue(tn, buf ^ 1);   // prefetch next tile

        const float* T = tile[buf];
        #pragma unroll
        for (int k4 = 0; k4 < 16; ++k4) {
            const int o = k4 * 4;          // imm-offset ds_read_b128, zero VALU
            const f32x4 a0 = *(const f32x4*)&T[ao0 + o];
            const f32x4 a1 = *(const f32x4*)&T[ao1 + o];
            const f32x4 a2 = *(const f32x4*)&T[ao2 + o];
            const f32x4 a3 = *(const f32x4*)&T[ao3 + o];
            const f32x4 b0 = *(const f32x4*)&T[bo0 + o];
            const f32x4 b1 = *(const f32x4*)&T[bo1 + o];
            const f32x4 b2 = *(const f32x4*)&T[bo2 + o];
            const f32x4 b3 = *(const f32x4*)&T[bo3 + o];
            acc[0][0]=dot4(a0,b0,acc[0][0]); acc[0][1]=dot4(a0,b1,acc[0][1]);
            acc[0][2]=dot4(a0,b2,acc[0][2]); acc[0][3]=dot4(a0,b3,acc[0][3]);
            acc[1][0]=dot4(a1,b0,acc[1][0]); acc[1][1]=dot4(a1,b1,acc[1][1]);
            acc[1][2]=dot4(a1,b2,acc[1][2]); acc[1][3]=dot4(a1,b3,acc[1][3]);
            acc[2][0]=dot4(a2,b0,acc[2][0]); acc[2][1]=dot4(a2,b1,acc[2][1]);
            acc[2][2]=dot4(a2,b2,acc[2][2]); acc[2][3]=dot4(a2,b3,acc[2][3]);
            acc[3][0]=dot4(a3,b0,acc[3][0]); acc[3][1]=dot4(a3,b1,acc[3][1]);
            acc[3][2]=dot4(a3,b2,acc[3][2]); acc[3][3]=dot4(a3,b3,acc[3][3]);
        }
        // channel sums: each thread sums 16 floats of one row (1.6% overhead)
        #pragma unroll
        for (int u = 0; u < 4; ++u) {
            const f32x4 v = *(const f32x4*)&T[soff + 4 * u];
            csum += (v.x + v.y) + (v.z + v.w);
        }
        __syncthreads();                   // next buffer ready; this one free
        buf ^= 1;
    }

    csum += __shfl_down(csum, 1, 4);
    csum += __shfl_down(csum, 2, 4);
    if ((tid & 3) == 0) atomicAdd(&ws[WS_SUM + g * 64 + (tid >> 2)], csum);

    float* Gp = ws + WS_G + g * 4096;
    #pragma unroll
    for (int iu = 0; iu < 4; ++iu)
        #pragma unroll
        for (int ju = 0; ju < 4; ++ju)
            atomicAdd(&Gp[(ri + 16 * iu) * 64 + (rj + 16 * ju)], acc[iu][ju]);
}

// ---------------------------------------------------------------------------
// Kernel 2: Sigma -> Newton-Schulz -> folded wm/beta. 4 blocks x 1024.
// ---------------------------------------------------------------------------
__device__ __forceinline__
void mm64(float* Cm, const float* Am, const float* Bm, int r, int c0) {
    f32x4 s = {0.f, 0.f, 0.f, 0.f};
    #pragma unroll
    for (int k4 = 0; k4 < 16; ++k4) {
        const f32x4 a  = *(const f32x4*)&Am[r * 68 + 4 * k4];
        const f32x4 b0 = *(const f32x4*)&Bm[(4 * k4 + 0) * 68 + c0];
        const f32x4 b1 = *(const f32x4*)&Bm[(4 * k4 + 1) * 68 + c0];
        const f32x4 b2 = *(const f32x4*)&Bm[(4 * k4 + 2) * 68 + c0];
        const f32x4 b3 = *(const f32x4*)&Bm[(4 * k4 + 3) * 68 + c0];
        s = fma4(a.x, b0, s); s = fma4(a.y, b1, s);
        s = fma4(a.z, b2, s); s = fma4(a.w, b3, s);
    }
    __syncthreads();
    *(f32x4*)&Cm[r * 68 + c0] = s;
    __syncthreads();
}

extern "C" __global__ __launch_bounds__(1024)
void k_solve(const float* __restrict__ weight, const float* __restrict__ bias,
             float* __restrict__ ws) {
    __shared__ __align__(16) float S [64 * 68];
    __shared__ __align__(16) float P [64 * 68];
    __shared__ __align__(16) float T1[64 * 68];
    __shared__ __align__(16) float mean_s[64];
    __shared__ float red;

    const int g   = blockIdx.x;
    const int tid = threadIdx.x;
    const int r   = tid >> 4;
    const int c0  = (tid & 15) << 2;

    const float* Gp = ws + WS_G + g * 4096;
    if (tid < 64) mean_s[tid] = ws[WS_SUM + g * 64 + tid] * (1.0f / Mf);
    __syncthreads();

    {
        const f32x4 gv = *(const f32x4*)&Gp[r * 64 + c0];
        const f32x4 mc = *(const f32x4*)&mean_s[c0];
        const float mr = mean_s[r];
        f32x4 sv, pv;
        #pragma unroll
        for (int j = 0; j < 4; ++j) {
            float v = gv[j] * (1.0f / Mf) - mr * mc[j];
            float p = 0.0f;
            if (c0 + j == r) { v += EPS_F; p = 1.0f; }
            sv[j] = v; pv[j] = p;
        }
        *(f32x4*)&S[r * 68 + c0] = sv;
        *(f32x4*)&P[r * 68 + c0] = pv;
    }
    __syncthreads();

    if (tid == 0) {
        float tr = 0.f;
        #pragma unroll
        for (int i = 0; i < 64; ++i) tr += S[i * 68 + i];
        red = 1.0f / tr;
    }
    __syncthreads();
    const float rtr = red;
    {
        f32x4 sv = *(const f32x4*)&S[r * 68 + c0];
        *(f32x4*)&S[r * 68 + c0] = sv * rtr;
    }
    __syncthreads();

    for (int it = 0; it < 5; ++it) {
        mm64(T1, P,  P, r, c0);            // T1 = P^2
        mm64(T1, T1, P, r, c0);            // T1 = P^3
        mm64(T1, T1, S, r, c0);            // T1 = P^3 * Sigma_N
        f32x4 pv = *(const f32x4*)&P [r * 68 + c0];
        f32x4 tv = *(const f32x4*)&T1[r * 68 + c0];
        *(f32x4*)&P[r * 68 + c0] = 1.5f * pv - 0.5f * tv;
        __syncthreads();
    }

    const float srtr = sqrtf(rtr);
    const float wrow = weight[g * 64 + r];
    float* Wp = ws + WS_WM + g * 4096;
    const f32x4 pv  = *(const f32x4*)&P[r * 68 + c0];
    const f32x4 wmv = pv * srtr;
    *(f32x4*)&Wp[r * 64 + c0] = wmv * wrow;
    const float part = wmv.x * mean_s[c0 + 0] + wmv.y * mean_s[c0 + 1]
                     + wmv.z * mean_s[c0 + 2] + wmv.w * mean_s[c0 + 3];
    T1[r * 68 + (tid & 15)] = part;
    __syncthreads();
    if (tid < 64) {
        float dot = 0.f;
        #pragma unroll
        for (int q = 0; q < 16; ++q) dot += T1[tid * 68 + q];
        ws[WS_BETA + g * 64 + tid] = bias[g * 64 + tid] - weight[g * 64 + tid] * dot;
    }
}

// ---------------------------------------------------------------------------
// Kernel 3: apply. grid (196,4) x 256. X tile linear [64][64] (row-uniform
// reads -> 2-way max); wm in padded [64][68] LDS.
// ---------------------------------------------------------------------------
extern "C" __global__ __launch_bounds__(256)
void k_apply(const float* __restrict__ X, const float* __restrict__ ws,
             float* __restrict__ out) {
    __shared__ __align__(16) float xt[2][64 * 64];
    __shared__ __align__(16) float wm_s[64 * 68];
    __shared__ float beta_s[64];

    const int g    = blockIdx.y;
    const int tid  = threadIdx.x;
    const int lane = tid & 63;
    const int w    = tid >> 6;
    const float* Xg = X + (size_t)g * 64 * HWc;

    {   // stage folded wm + beta
        const float* Wp = ws + WS_WM + g * 4096;
        const int rr = tid >> 2, qq = tid & 3;
        #pragma unroll
        for (int j = 0; j < 4; ++j)
            *(f32x4*)&wm_s[rr * 68 + qq * 16 + 4 * j] =
                *(const f32x4*)&Wp[rr * 64 + qq * 16 + 4 * j];
        if (tid < 64) beta_s[tid] = ws[WS_BETA + g * 64 + tid];
    }

    int goff[4], lbase[4];
    #pragma unroll
    for (int q = 0; q < 4; ++q) {
        const int inst = w * 4 + q;
        const int gr   = inst * 64 + lane;
        goff[q]  = (gr >> 4) * HWc + (gr & 15) * 4;
        lbase[q] = inst * 256;
    }

    auto issue = [&](int t, int b) {
        const int bb  = t / 49;
        const int hw0 = (t - bb * 49) << 6;
        const float* src = Xg + (size_t)bb * CHW + hw0;
        float* dst = xt[b];
        #pragma unroll
        for (int q = 0; q < 4; ++q) gload_lds16(src + goff[q], dst + lbase[q]);
    };

    const int ri = tid >> 4, rj = tid & 15;
    const int w0o = (ri     ) * 68, w1o = (ri + 16) * 68,
              w2o = (ri + 32) * 68, w3o = (ri + 48) * 68;
    const int xo = rj * 4;
    const size_t co0 = (size_t)(g * 64 + ri     ) * HWc + xo;
    const size_t co1 = (size_t)(g * 64 + ri + 16) * HWc + xo;
    const size_t co2 = (size_t)(g * 64 + ri + 32) * HWc + xo;
    const size_t co3 = (size_t)(g * 64 + ri + 48) * HWc + xo;

    int t = blockIdx.x;
    issue(t, 0);
    __syncthreads();
    int buf = 0;
    for (; t < NT; t += GX) {
        const int tn = t + GX;
        if (tn < NT) issue(tn, buf ^ 1);

        const float* T = xt[buf];
        f32x4 acc0 = {0,0,0,0}, acc1 = {0,0,0,0}, acc2 = {0,0,0,0}, acc3 = {0,0,0,0};
        #pragma unroll
        for (int k4 = 0; k4 < 16; ++k4) {
            const f32x4 wv0 = *(const f32x4*)&wm_s[w0o + 4 * k4];
            const f32x4 wv1 = *(const f32x4*)&wm_s[w1o + 4 * k4];
            const f32x4 wv2 = *(const f32x4*)&wm_s[w2o + 4 * k4];
            const f32x4 wv3 = *(const f32x4*)&wm_s[w3o + 4 * k4];
            const f32x4 x0 = *(const f32x4*)&T[(4 * k4 + 0) * 64 + xo];
            const f32x4 x1 = *(const f32x4*)&T[(4 * k4 + 1) * 64 + xo];
            const f32x4 x2 = *(const f32x4*)&T[(4 * k4 + 2) * 64 + xo];
            const f32x4 x3 = *(const f32x4*)&T[(4 * k4 + 3) * 64 + xo];
            acc0 = fma4(wv0.x, x0, fma4(wv0.y, x1, fma4(wv0.z, x2, fma4(wv0.w, x3, acc0))));
            acc1 = fma4(wv1.x, x0, fma4(wv1.y, x1, fma4(wv1.z, x2, fma4(wv1.w, x3, acc1))));
            acc2 = fma4(wv2.x, x0, fma4(wv2.y, x1, fma4(wv2.z, x2, fma4(wv2.w, x3, acc2))));
            acc3 = fma4(wv3.x, x0, fma4(wv3.y, x1, fma4(wv3.z, x2, fma4(wv3.w, x3, acc3))));
        }

        const int bb  = t / 49;
        const int hw0 = (t - bb * 49) << 6;
        float* ob = out + (size_t)bb * CHW + hw0;
        *(f32x4*)(ob + co0) = acc0 + beta_s[ri     ];
        *(f32x4*)(ob + co1) = acc1 + beta_s[ri + 16];
        *(f32x4*)(ob + co2) = acc2 + beta_s[ri + 32];
        *(f32x4*)(ob + co3) = acc3 + beta_s[ri + 48];

        __syncthreads();
        buf ^= 1;
    }
}

// ---------------------------------------------------------------------------
extern "C" void kernel_launch(void* const* d_in, const int* in_sizes, int n_in,
                              void* d_out, int out_size, void* d_ws, size_t ws_size,
                              hipStream_t stream) {
    const float* X      = (const float*)d_in[0];
    const float* weight = (const float*)d_in[1];
    const float* bias   = (const float*)d_in[2];
    float* out = (float*)d_out;
    float* ws  = (float*)d_ws;

    hipMemsetAsync(ws, 0, (size_t)WS_ZERO_FLOATS * sizeof(float), stream);

    hipLaunchKernelGGL(k_gram,  dim3(GX, 4), dim3(256),  0, stream, X, ws);
    hipLaunchKernelGGL(k_solve, dim3(4),     dim3(1024), 0, stream, weight, bias, ws);
    hipLaunchKernelGGL(k_apply, dim3(GX, 4), dim3(256),  0, stream, X, ws, out);
}

// Round 3
// 186.086 us; speedup vs baseline: 2.2350x; 1.7595x over previous
//
#include <hip/hip_runtime.h>
#include <math.h>

// ---------------------------------------------------------------------------
// IterNorm (64,256,56,56) fp32, g=4 groups of 64 channels.
//  k_gram : G = X_g X_g^T via bf16 MFMA (fp32 accum) + fp32 channel sums
//  k_solve: Sigma=G/m-mu mu^T+eps I; Newton-Schulz x5 (commuting form, 13 mm);
//           fold weight/bias/mean into wm/beta
//  k_apply: out = wm_bf16 * x_bf16 + beta via MFMA, transposed-x LDS tile
// MFMA 16x16x32_bf16 layouts (HW-verified): A/B-frag lane l: row l&15,
// k=(l>>4)*8+j ; C/D: col=l&15, row=(l>>4)*4+reg.
// ---------------------------------------------------------------------------

#define EPS_F 1e-5f

using f32x4v = __attribute__((ext_vector_type(4))) float;
using short8 = __attribute__((ext_vector_type(8))) short;
using u32x4  = __attribute__((ext_vector_type(4))) unsigned int;

constexpr int Cc  = 256;
constexpr int HWc = 3136;                 // 56*56
constexpr int CHW = Cc * HWc;             // 802816
constexpr float Mf = 200704.0f;           // 64*3136
constexpr int GX  = 196;                  // 3136 tiles / 196 = 16 tiles/block
constexpr int LDB = 72;                   // bf16 LDS row stride (144 B, 16B-aligned)

// workspace layout (float offsets)
constexpr int WS_G    = 0;       // 4*64*64 Gram accumulators
constexpr int WS_SUM  = 16384;   // 256 channel sums
constexpr int WS_WM   = 16640;   // 4*64*64 folded whitening matrices (fp32)
constexpr int WS_BETA = 33024;   // 256 folded bias
constexpr int WS_ZERO_FLOATS = 16640;

__device__ __forceinline__ unsigned bfpack2(float a, float b) {
    // RNE fp32->bf16, pack (a=low, b=high)
    unsigned ua = __builtin_bit_cast(unsigned, a);
    unsigned ub = __builtin_bit_cast(unsigned, b);
    ua = ua + 0x7FFFu + ((ua >> 16) & 1u);
    ub = ub + 0x7FFFu + ((ub >> 16) & 1u);
    return (ua >> 16) | (ub & 0xFFFF0000u);
}

__device__ __forceinline__ f32x4v mfma16(short8 a, short8 b, f32x4v c) {
    return __builtin_amdgcn_mfma_f32_16x16x32_bf16(a, b, c, 0, 0, 0);
}

// ---------------------------------------------------------------------------
// Kernel 1: Gram via MFMA. grid (196,4) x 256 (4 waves).
// LDS tile [64 c][72 bf16] (m contiguous). Wave w owns 2x2 of the 4x4
// 16x16 output blocks. Per tile: 8 ds_read_b128 + 8 mfma per wave.
// ---------------------------------------------------------------------------
extern "C" __global__ __launch_bounds__(256)
void k_gram(const float* __restrict__ X, float* __restrict__ ws) {
    __shared__ __align__(16) unsigned short tg[2][64 * LDB];
    const int g = blockIdx.y, tid = threadIdx.x;
    const int lane = tid & 63, w = tid >> 6;
    const int row = tid >> 2, mo = (tid & 3) << 4;     // load mapping
    const int l15 = lane & 15, lg = lane >> 4;
    const int CBi0 = (w >> 1) << 1, CBj0 = (w & 1) << 1;
    const float* Xg = X + (size_t)g * 64 * HWc;

    f32x4v acc[2][2];
    #pragma unroll
    for (int i = 0; i < 2; ++i)
        #pragma unroll
        for (int j = 0; j < 2; ++j) acc[i][j] = (f32x4v){0.f, 0.f, 0.f, 0.f};
    float csum = 0.0f;

    f32x4v cur[4];
    {
        const int t = blockIdx.x, b = t / 49, hw0 = (t - b * 49) << 6;
        const float* p = Xg + (size_t)b * CHW + (size_t)row * HWc + hw0 + mo;
        cur[0] = *(const f32x4v*)(p);      cur[1] = *(const f32x4v*)(p + 4);
        cur[2] = *(const f32x4v*)(p + 8);  cur[3] = *(const f32x4v*)(p + 12);
    }

    int buf = 0;
    for (int k = 0; k < 16; ++k) {
        unsigned pk[8];
        #pragma unroll
        for (int i = 0; i < 4; ++i) {
            csum += (cur[i].x + cur[i].y) + (cur[i].z + cur[i].w);
            pk[2*i]   = bfpack2(cur[i].x, cur[i].y);
            pk[2*i+1] = bfpack2(cur[i].z, cur[i].w);
        }
        unsigned short* dst = &tg[buf][row * LDB + mo];
        *(u32x4*)(dst)     = (u32x4){pk[0], pk[1], pk[2], pk[3]};
        *(u32x4*)(dst + 8) = (u32x4){pk[4], pk[5], pk[6], pk[7]};
        __syncthreads();

        if (k < 15) {                       // prefetch next tile into regs
            const int t = blockIdx.x + GX * (k + 1);
            const int b = t / 49, hw0 = (t - b * 49) << 6;
            const float* p = Xg + (size_t)b * CHW + (size_t)row * HWc + hw0 + mo;
            cur[0] = *(const f32x4v*)(p);      cur[1] = *(const f32x4v*)(p + 4);
            cur[2] = *(const f32x4v*)(p + 8);  cur[3] = *(const f32x4v*)(p + 12);
        }

        const unsigned short* T = tg[buf];
        #pragma unroll
        for (int s = 0; s < 2; ++s) {
            const int ko = 8 * lg + 32 * s;
            const short8 a0 = *(const short8*)&T[(CBi0 * 16      + l15) * LDB + ko];
            const short8 a1 = *(const short8*)&T[((CBi0+1) * 16  + l15) * LDB + ko];
            const short8 b0 = *(const short8*)&T[(CBj0 * 16      + l15) * LDB + ko];
            const short8 b1 = *(const short8*)&T[((CBj0+1) * 16  + l15) * LDB + ko];
            acc[0][0] = mfma16(a0, b0, acc[0][0]);
            acc[0][1] = mfma16(a0, b1, acc[0][1]);
            acc[1][0] = mfma16(a1, b0, acc[1][0]);
            acc[1][1] = mfma16(a1, b1, acc[1][1]);
        }
        buf ^= 1;
    }

    csum += __shfl_down(csum, 1, 4);
    csum += __shfl_down(csum, 2, 4);
    if ((tid & 3) == 0) atomicAdd(&ws[WS_SUM + g * 64 + row], csum);

    float* Gp = ws + WS_G + g * 4096;
    #pragma unroll
    for (int ci = 0; ci < 2; ++ci)
        #pragma unroll
        for (int cj = 0; cj < 2; ++cj)
            #pragma unroll
            for (int reg = 0; reg < 4; ++reg) {
                const int r = (CBi0 + ci) * 16 + lg * 4 + reg;
                const int c = (CBj0 + cj) * 16 + l15;
                atomicAdd(&Gp[r * 64 + c], acc[ci][cj][reg]);
            }
}

// ---------------------------------------------------------------------------
// Kernel 2: Newton-Schulz, fp32, 4 blocks x 256. Commuting form:
// M0=Sigma_N; per iter: W=1.5I-0.5M; P<-P*W; M<-(M*W)*W (skip M on last).
// 13 matmuls of 64^3, 4x4 contiguous microtile (broadcast-friendly).
// ---------------------------------------------------------------------------
__device__ __forceinline__
void mm64s(float* C, const float* A, const float* B, int r0, int c0) {
    f32x4v s[4] = {{0,0,0,0},{0,0,0,0},{0,0,0,0},{0,0,0,0}};
    #pragma unroll 4
    for (int kk = 0; kk < 16; ++kk) {
        const f32x4v b0 = *(const f32x4v*)&B[(4*kk + 0) * 68 + c0];
        const f32x4v b1 = *(const f32x4v*)&B[(4*kk + 1) * 68 + c0];
        const f32x4v b2 = *(const f32x4v*)&B[(4*kk + 2) * 68 + c0];
        const f32x4v b3 = *(const f32x4v*)&B[(4*kk + 3) * 68 + c0];
        #pragma unroll
        for (int i = 0; i < 4; ++i) {
            const f32x4v a = *(const f32x4v*)&A[(r0 + i) * 68 + 4 * kk];
            s[i] += a.x * b0 + a.y * b1 + a.z * b2 + a.w * b3;
        }
    }
    __syncthreads();
    #pragma unroll
    for (int i = 0; i < 4; ++i) *(f32x4v*)&C[(r0 + i) * 68 + c0] = s[i];
    __syncthreads();
}

extern "C" __global__ __launch_bounds__(256)
void k_solve(const float* __restrict__ weight, const float* __restrict__ bias,
             float* __restrict__ ws) {
    __shared__ __align__(16) float M [64 * 68];
    __shared__ __align__(16) float P [64 * 68];
    __shared__ __align__(16) float W [64 * 68];
    __shared__ __align__(16) float T1[64 * 68];
    __shared__ __align__(16) float mean_s[64];
    __shared__ float red;

    const int g = blockIdx.x, tid = threadIdx.x;
    const int r = tid >> 2, ch = (tid & 3) << 4;       // elementwise mapping
    const int r0 = (tid >> 4) << 2, c0 = (tid & 15) << 2; // mm mapping

    if (tid < 64) mean_s[tid] = ws[WS_SUM + g * 64 + tid] * (1.0f / Mf);
    __syncthreads();

    const float* Gp = ws + WS_G + g * 4096;
    const float mr = mean_s[r];
    #pragma unroll
    for (int j4 = 0; j4 < 4; ++j4) {
        const int c = ch + 4 * j4;
        const f32x4v gv = *(const f32x4v*)&Gp[r * 64 + c];
        const f32x4v mc = *(const f32x4v*)&mean_s[c];
        f32x4v sv, pv = {0,0,0,0};
        #pragma unroll
        for (int j = 0; j < 4; ++j) {
            float v = gv[j] * (1.0f / Mf) - mr * mc[j];
            if (c + j == r) { v += EPS_F; pv[j] = 1.0f; }
            sv[j] = v;
        }
        *(f32x4v*)&M[r * 68 + c] = sv;
        *(f32x4v*)&P[r * 68 + c] = pv;
    }
    __syncthreads();

    if (tid == 0) {
        float tr = 0.f;
        #pragma unroll
        for (int i = 0; i < 64; ++i) tr += M[i * 68 + i];
        red = 1.0f / tr;
    }
    __syncthreads();
    const float rtr = red;
    #pragma unroll
    for (int j4 = 0; j4 < 4; ++j4) {
        const int c = ch + 4 * j4;
        *(f32x4v*)&M[r * 68 + c] = *(const f32x4v*)&M[r * 68 + c] * rtr;
    }
    __syncthreads();

    for (int t = 0; t < 5; ++t) {
        #pragma unroll
        for (int j4 = 0; j4 < 4; ++j4) {     // W = 1.5I - 0.5M
            const int c = ch + 4 * j4;
            f32x4v mv = *(const f32x4v*)&M[r * 68 + c];
            f32x4v wv = -0.5f * mv;
            #pragma unroll
            for (int j = 0; j < 4; ++j) if (c + j == r) wv[j] += 1.5f;
            *(f32x4v*)&W[r * 68 + c] = wv;
        }
        __syncthreads();
        mm64s(P, P, W, r0, c0);              // P <- P*W (alias-safe)
        if (t < 4) {
            mm64s(T1, M, W, r0, c0);         // T1 = M*W
            mm64s(M, T1, W, r0, c0);         // M  = T1*W
        }
    }

    const float srtr = sqrtf(rtr);
    const float wr = weight[g * 64 + r];
    float* Wp = ws + WS_WM + g * 4096;
    float part = 0.0f;
    #pragma unroll
    for (int j4 = 0; j4 < 4; ++j4) {
        const int c = ch + 4 * j4;
        const f32x4v pv = *(const f32x4v*)&P[r * 68 + c] * srtr;
        *(f32x4v*)&Wp[r * 64 + c] = pv * wr;
        const f32x4v mc = *(const f32x4v*)&mean_s[c];
        part += pv.x * mc.x + pv.y * mc.y + pv.z * mc.z + pv.w * mc.w;
    }
    part += __shfl_down(part, 1, 4);
    part += __shfl_down(part, 2, 4);
    if ((tid & 3) == 0)
        ws[WS_BETA + g * 64 + r] = bias[g * 64 + r] - wr * part;
}

// ---------------------------------------------------------------------------
// Kernel 3: apply via MFMA. grid (196,4) x 256. Transposed x tile TX[m][e]
// built from 16 per-e coalesced dword loads (lane=m) -> lane holds e-slices.
// wm a-frags + beta hoisted out of loop. 4 ds_read + 8 mfma per tile/wave.
// ---------------------------------------------------------------------------
extern "C" __global__ __launch_bounds__(256)
void k_apply(const float* __restrict__ X, const float* __restrict__ ws,
             float* __restrict__ out) {
    __shared__ __align__(16) unsigned short tx[2][64 * LDB];
    __shared__ __align__(16) unsigned short wm_s[64 * LDB];

    const int g = blockIdx.y, tid = threadIdx.x;
    const int lane = tid & 63, w = tid >> 6;
    const int l15 = lane & 15, lg = lane >> 4;
    const float* Xg = X + (size_t)g * 64 * HWc;

    {   // stage wm fp32 -> bf16
        const float* Wp = ws + WS_WM + g * 4096;
        const int r = tid >> 2, ch = (tid & 3) << 4;
        const float* p = Wp + r * 64 + ch;
        const f32x4v v0 = *(const f32x4v*)(p);      const f32x4v v1 = *(const f32x4v*)(p + 4);
        const f32x4v v2 = *(const f32x4v*)(p + 8);  const f32x4v v3 = *(const f32x4v*)(p + 12);
        unsigned short* dst = &wm_s[r * LDB + ch];
        *(u32x4*)(dst)     = (u32x4){bfpack2(v0.x,v0.y), bfpack2(v0.z,v0.w),
                                     bfpack2(v1.x,v1.y), bfpack2(v1.z,v1.w)};
        *(u32x4*)(dst + 8) = (u32x4){bfpack2(v2.x,v2.y), bfpack2(v2.z,v2.w),
                                     bfpack2(v3.x,v3.y), bfpack2(v3.z,v3.w)};
    }
    __syncthreads();

    const int CB0 = (w >> 1) << 1, MB0 = (w & 1) << 1;
    short8 afrag[2][2];
    #pragma unroll
    for (int ci = 0; ci < 2; ++ci)
        #pragma unroll
        for (int s = 0; s < 2; ++s)
            afrag[ci][s] = *(const short8*)&wm_s[((CB0 + ci) * 16 + l15) * LDB + 8 * lg + 32 * s];

    float betav[2][4]; size_t crow[2][4];
    #pragma unroll
    for (int ci = 0; ci < 2; ++ci)
        #pragma unroll
        for (int reg = 0; reg < 4; ++reg) {
            const int cl = (CB0 + ci) * 16 + lg * 4 + reg;
            betav[ci][reg] = ws[WS_BETA + g * 64 + cl];
            crow[ci][reg]  = (size_t)(g * 64 + cl) * HWc;
        }
    const int mcol0 = MB0 * 16 + l15, mcol1 = (MB0 + 1) * 16 + l15;

    const int e0 = w * 16;
    float cur[16];
    {
        const int t = blockIdx.x, b = t / 49, hw0 = (t - b * 49) << 6;
        const float* p = Xg + (size_t)b * CHW + (size_t)e0 * HWc + hw0 + lane;
        #pragma unroll
        for (int j = 0; j < 16; ++j) cur[j] = p[(size_t)j * HWc];
    }

    int buf = 0;
    for (int k = 0; k < 16; ++k) {
        const int t = blockIdx.x + GX * k;
        const int b = t / 49, hw0 = (t - b * 49) << 6;

        unsigned short* dst = &tx[buf][lane * LDB + e0];
        *(u32x4*)(dst)     = (u32x4){bfpack2(cur[0],cur[1]),  bfpack2(cur[2],cur[3]),
                                     bfpack2(cur[4],cur[5]),  bfpack2(cur[6],cur[7])};
        *(u32x4*)(dst + 8) = (u32x4){bfpack2(cur[8],cur[9]),  bfpack2(cur[10],cur[11]),
                                     bfpack2(cur[12],cur[13]),bfpack2(cur[14],cur[15])};
        __syncthreads();

        if (k < 15) {                        // prefetch next tile into regs
            const int tn = t + GX, bn = tn / 49, hwn = (tn - bn * 49) << 6;
            const float* p = Xg + (size_t)bn * CHW + (size_t)e0 * HWc + hwn + lane;
            #pragma unroll
            for (int j = 0; j < 16; ++j) cur[j] = p[(size_t)j * HWc];
        }

        f32x4v acc[2][2];
        #pragma unroll
        for (int i = 0; i < 2; ++i)
            #pragma unroll
            for (int j = 0; j < 2; ++j) acc[i][j] = (f32x4v){0.f,0.f,0.f,0.f};

        const unsigned short* T = tx[buf];
        #pragma unroll
        for (int s = 0; s < 2; ++s) {
            const int ko = 8 * lg + 32 * s;
            const short8 b0 = *(const short8*)&T[(MB0 * 16     + l15) * LDB + ko];
            const short8 b1 = *(const short8*)&T[((MB0+1) * 16 + l15) * LDB + ko];
            acc[0][0] = mfma16(afrag[0][s], b0, acc[0][0]);
            acc[0][1] = mfma16(afrag[0][s], b1, acc[0][1]);
            acc[1][0] = mfma16(afrag[1][s], b0, acc[1][0]);
            acc[1][1] = mfma16(afrag[1][s], b1, acc[1][1]);
        }

        float* ob = out + (size_t)b * CHW + hw0;
        #pragma unroll
        for (int ci = 0; ci < 2; ++ci)
            #pragma unroll
            for (int reg = 0; reg < 4; ++reg) {
                ob[crow[ci][reg] + mcol0] = acc[ci][0][reg] + betav[ci][reg];
                ob[crow[ci][reg] + mcol1] = acc[ci][1][reg] + betav[ci][reg];
            }
        buf ^= 1;
    }
}

// ---------------------------------------------------------------------------
extern "C" void kernel_launch(void* const* d_in, const int* in_sizes, int n_in,
                              void* d_out, int out_size, void* d_ws, size_t ws_size,
                              hipStream_t stream) {
    const float* X      = (const float*)d_in[0];
    const float* weight = (const float*)d_in[1];
    const float* bias   = (const float*)d_in[2];
    float* out = (float*)d_out;
    float* ws  = (float*)d_ws;

    hipMemsetAsync(ws, 0, (size_t)WS_ZERO_FLOATS * sizeof(float), stream);

    hipLaunchKernelGGL(k_gram,  dim3(GX, 4), dim3(256), 0, stream, X, ws);
    hipLaunchKernelGGL(k_solve, dim3(4),     dim3(256), 0, stream, weight, bias, ws);
    hipLaunchKernelGGL(k_apply, dim3(GX, 4), dim3(256), 0, stream, X, ws, out);
}

// Round 4
// 185.314 us; speedup vs baseline: 2.2444x; 1.0042x over previous
//
#include <hip/hip_runtime.h>
#include <math.h>

// ---------------------------------------------------------------------------
// IterNorm (64,256,56,56) fp32, g=4 groups of 64 channels.
//  k_zero : zero Gram/sum accumulators (replaces pathological 120us
//           __amd_rocclr_fillBufferAligned from hipMemsetAsync)
//  k_gram : G = X_g X_g^T via bf16 MFMA (fp32 accum) + fp32 channel sums
//  k_solve: Sigma=G/m-mu mu^T+eps I; Newton-Schulz x5 (commuting form, 13 mm);
//           fold weight/bias/mean into wm/beta
//  k_apply: out = wm_bf16 * x_bf16 + beta via MFMA, transposed-x LDS tile
// MFMA 16x16x32_bf16 layouts (HW-verified): A/B-frag lane l: row l&15,
// k=(l>>4)*8+j ; C/D: col=l&15, row=(l>>4)*4+reg.
// ---------------------------------------------------------------------------

#define EPS_F 1e-5f

using f32x4v = __attribute__((ext_vector_type(4))) float;
using short8 = __attribute__((ext_vector_type(8))) short;
using u32x4  = __attribute__((ext_vector_type(4))) unsigned int;

constexpr int Cc  = 256;
constexpr int HWc = 3136;                 // 56*56
constexpr int CHW = Cc * HWc;             // 802816
constexpr float Mf = 200704.0f;           // 64*3136
constexpr int GX  = 196;                  // 3136 tiles / 196 = 16 tiles/block
constexpr int LDB = 72;                   // bf16 LDS row stride (144 B, 16B-aligned)

// workspace layout (float offsets)
constexpr int WS_G    = 0;       // 4*64*64 Gram accumulators
constexpr int WS_SUM  = 16384;   // 256 channel sums
constexpr int WS_WM   = 16640;   // 4*64*64 folded whitening matrices (fp32)
constexpr int WS_BETA = 33024;   // 256 folded bias
constexpr int WS_ZERO_FLOATS = 16640;     // 4160 float4s

__device__ __forceinline__ unsigned bfpack2(float a, float b) {
    // RNE fp32->bf16, pack (a=low, b=high)
    unsigned ua = __builtin_bit_cast(unsigned, a);
    unsigned ub = __builtin_bit_cast(unsigned, b);
    ua = ua + 0x7FFFu + ((ua >> 16) & 1u);
    ub = ub + 0x7FFFu + ((ub >> 16) & 1u);
    return (ua >> 16) | (ub & 0xFFFF0000u);
}

__device__ __forceinline__ f32x4v mfma16(short8 a, short8 b, f32x4v c) {
    return __builtin_amdgcn_mfma_f32_16x16x32_bf16(a, b, c, 0, 0, 0);
}

// ---------------------------------------------------------------------------
// Kernel 0: zero the accumulator region. 17 blocks x 256 x float4 = 17408
// float4 slots >= 4160 needed. ~2-4us vs 120us for runtime fill.
// ---------------------------------------------------------------------------
extern "C" __global__ __launch_bounds__(256)
void k_zero(float* __restrict__ ws) {
    const int i = blockIdx.x * 256 + threadIdx.x;
    if (i < WS_ZERO_FLOATS / 4)
        *(f32x4v*)&ws[i * 4] = (f32x4v){0.f, 0.f, 0.f, 0.f};
}

// ---------------------------------------------------------------------------
// Kernel 1: Gram via MFMA. grid (196,4) x 256 (4 waves).
// LDS tile [64 c][72 bf16] (m contiguous). Wave w owns 2x2 of the 4x4
// 16x16 output blocks. Per tile: 8 ds_read_b128 + 8 mfma per wave.
// ---------------------------------------------------------------------------
extern "C" __global__ __launch_bounds__(256)
void k_gram(const float* __restrict__ X, float* __restrict__ ws) {
    __shared__ __align__(16) unsigned short tg[2][64 * LDB];
    const int g = blockIdx.y, tid = threadIdx.x;
    const int lane = tid & 63, w = tid >> 6;
    const int row = tid >> 2, mo = (tid & 3) << 4;     // load mapping
    const int l15 = lane & 15, lg = lane >> 4;
    const int CBi0 = (w >> 1) << 1, CBj0 = (w & 1) << 1;
    const float* Xg = X + (size_t)g * 64 * HWc;

    f32x4v acc[2][2];
    #pragma unroll
    for (int i = 0; i < 2; ++i)
        #pragma unroll
        for (int j = 0; j < 2; ++j) acc[i][j] = (f32x4v){0.f, 0.f, 0.f, 0.f};
    float csum = 0.0f;

    f32x4v cur[4];
    {
        const int t = blockIdx.x, b = t / 49, hw0 = (t - b * 49) << 6;
        const float* p = Xg + (size_t)b * CHW + (size_t)row * HWc + hw0 + mo;
        cur[0] = *(const f32x4v*)(p);      cur[1] = *(const f32x4v*)(p + 4);
        cur[2] = *(const f32x4v*)(p + 8);  cur[3] = *(const f32x4v*)(p + 12);
    }

    int buf = 0;
    for (int k = 0; k < 16; ++k) {
        unsigned pk[8];
        #pragma unroll
        for (int i = 0; i < 4; ++i) {
            csum += (cur[i].x + cur[i].y) + (cur[i].z + cur[i].w);
            pk[2*i]   = bfpack2(cur[i].x, cur[i].y);
            pk[2*i+1] = bfpack2(cur[i].z, cur[i].w);
        }
        unsigned short* dst = &tg[buf][row * LDB + mo];
        *(u32x4*)(dst)     = (u32x4){pk[0], pk[1], pk[2], pk[3]};
        *(u32x4*)(dst + 8) = (u32x4){pk[4], pk[5], pk[6], pk[7]};
        __syncthreads();

        if (k < 15) {                       // prefetch next tile into regs
            const int t = blockIdx.x + GX * (k + 1);
            const int b = t / 49, hw0 = (t - b * 49) << 6;
            const float* p = Xg + (size_t)b * CHW + (size_t)row * HWc + hw0 + mo;
            cur[0] = *(const f32x4v*)(p);      cur[1] = *(const f32x4v*)(p + 4);
            cur[2] = *(const f32x4v*)(p + 8);  cur[3] = *(const f32x4v*)(p + 12);
        }

        const unsigned short* T = tg[buf];
        #pragma unroll
        for (int s = 0; s < 2; ++s) {
            const int ko = 8 * lg + 32 * s;
            const short8 a0 = *(const short8*)&T[(CBi0 * 16      + l15) * LDB + ko];
            const short8 a1 = *(const short8*)&T[((CBi0+1) * 16  + l15) * LDB + ko];
            const short8 b0 = *(const short8*)&T[(CBj0 * 16      + l15) * LDB + ko];
            const short8 b1 = *(const short8*)&T[((CBj0+1) * 16  + l15) * LDB + ko];
            acc[0][0] = mfma16(a0, b0, acc[0][0]);
            acc[0][1] = mfma16(a0, b1, acc[0][1]);
            acc[1][0] = mfma16(a1, b0, acc[1][0]);
            acc[1][1] = mfma16(a1, b1, acc[1][1]);
        }
        buf ^= 1;
    }

    csum += __shfl_down(csum, 1, 4);
    csum += __shfl_down(csum, 2, 4);
    if ((tid & 3) == 0) atomicAdd(&ws[WS_SUM + g * 64 + row], csum);

    float* Gp = ws + WS_G + g * 4096;
    #pragma unroll
    for (int ci = 0; ci < 2; ++ci)
        #pragma unroll
        for (int cj = 0; cj < 2; ++cj)
            #pragma unroll
            for (int reg = 0; reg < 4; ++reg) {
                const int r = (CBi0 + ci) * 16 + lg * 4 + reg;
                const int c = (CBj0 + cj) * 16 + l15;
                atomicAdd(&Gp[r * 64 + c], acc[ci][cj][reg]);
            }
}

// ---------------------------------------------------------------------------
// Kernel 2: Newton-Schulz, fp32, 4 blocks x 256. Commuting form:
// M0=Sigma_N; per iter: W=1.5I-0.5M; P<-P*W; M<-(M*W)*W (skip M on last).
// 13 matmuls of 64^3, 4x4 contiguous microtile (broadcast-friendly).
// ---------------------------------------------------------------------------
__device__ __forceinline__
void mm64s(float* C, const float* A, const float* B, int r0, int c0) {
    f32x4v s[4] = {{0,0,0,0},{0,0,0,0},{0,0,0,0},{0,0,0,0}};
    #pragma unroll 4
    for (int kk = 0; kk < 16; ++kk) {
        const f32x4v b0 = *(const f32x4v*)&B[(4*kk + 0) * 68 + c0];
        const f32x4v b1 = *(const f32x4v*)&B[(4*kk + 1) * 68 + c0];
        const f32x4v b2 = *(const f32x4v*)&B[(4*kk + 2) * 68 + c0];
        const f32x4v b3 = *(const f32x4v*)&B[(4*kk + 3) * 68 + c0];
        #pragma unroll
        for (int i = 0; i < 4; ++i) {
            const f32x4v a = *(const f32x4v*)&A[(r0 + i) * 68 + 4 * kk];
            s[i] += a.x * b0 + a.y * b1 + a.z * b2 + a.w * b3;
        }
    }
    __syncthreads();
    #pragma unroll
    for (int i = 0; i < 4; ++i) *(f32x4v*)&C[(r0 + i) * 68 + c0] = s[i];
    __syncthreads();
}

extern "C" __global__ __launch_bounds__(256)
void k_solve(const float* __restrict__ weight, const float* __restrict__ bias,
             float* __restrict__ ws) {
    __shared__ __align__(16) float M [64 * 68];
    __shared__ __align__(16) float P [64 * 68];
    __shared__ __align__(16) float W [64 * 68];
    __shared__ __align__(16) float T1[64 * 68];
    __shared__ __align__(16) float mean_s[64];
    __shared__ float red;

    const int g = blockIdx.x, tid = threadIdx.x;
    const int r = tid >> 2, ch = (tid & 3) << 4;       // elementwise mapping
    const int r0 = (tid >> 4) << 2, c0 = (tid & 15) << 2; // mm mapping

    if (tid < 64) mean_s[tid] = ws[WS_SUM + g * 64 + tid] * (1.0f / Mf);
    __syncthreads();

    const float* Gp = ws + WS_G + g * 4096;
    const float mr = mean_s[r];
    #pragma unroll
    for (int j4 = 0; j4 < 4; ++j4) {
        const int c = ch + 4 * j4;
        const f32x4v gv = *(const f32x4v*)&Gp[r * 64 + c];
        const f32x4v mc = *(const f32x4v*)&mean_s[c];
        f32x4v sv, pv = {0,0,0,0};
        #pragma unroll
        for (int j = 0; j < 4; ++j) {
            float v = gv[j] * (1.0f / Mf) - mr * mc[j];
            if (c + j == r) { v += EPS_F; pv[j] = 1.0f; }
            sv[j] = v;
        }
        *(f32x4v*)&M[r * 68 + c] = sv;
        *(f32x4v*)&P[r * 68 + c] = pv;
    }
    __syncthreads();

    if (tid == 0) {
        float tr = 0.f;
        #pragma unroll
        for (int i = 0; i < 64; ++i) tr += M[i * 68 + i];
        red = 1.0f / tr;
    }
    __syncthreads();
    const float rtr = red;
    #pragma unroll
    for (int j4 = 0; j4 < 4; ++j4) {
        const int c = ch + 4 * j4;
        *(f32x4v*)&M[r * 68 + c] = *(const f32x4v*)&M[r * 68 + c] * rtr;
    }
    __syncthreads();

    for (int t = 0; t < 5; ++t) {
        #pragma unroll
        for (int j4 = 0; j4 < 4; ++j4) {     // W = 1.5I - 0.5M
            const int c = ch + 4 * j4;
            f32x4v mv = *(const f32x4v*)&M[r * 68 + c];
            f32x4v wv = -0.5f * mv;
            #pragma unroll
            for (int j = 0; j < 4; ++j) if (c + j == r) wv[j] += 1.5f;
            *(f32x4v*)&W[r * 68 + c] = wv;
        }
        __syncthreads();
        mm64s(P, P, W, r0, c0);              // P <- P*W (alias-safe)
        if (t < 4) {
            mm64s(T1, M, W, r0, c0);         // T1 = M*W
            mm64s(M, T1, W, r0, c0);         // M  = T1*W
        }
    }

    const float srtr = sqrtf(rtr);
    const float wr = weight[g * 64 + r];
    float* Wp = ws + WS_WM + g * 4096;
    float part = 0.0f;
    #pragma unroll
    for (int j4 = 0; j4 < 4; ++j4) {
        const int c = ch + 4 * j4;
        const f32x4v pv = *(const f32x4v*)&P[r * 68 + c] * srtr;
        *(f32x4v*)&Wp[r * 64 + c] = pv * wr;
        const f32x4v mc = *(const f32x4v*)&mean_s[c];
        part += pv.x * mc.x + pv.y * mc.y + pv.z * mc.z + pv.w * mc.w;
    }
    part += __shfl_down(part, 1, 4);
    part += __shfl_down(part, 2, 4);
    if ((tid & 3) == 0)
        ws[WS_BETA + g * 64 + r] = bias[g * 64 + r] - wr * part;
}

// ---------------------------------------------------------------------------
// Kernel 3: apply via MFMA. grid (196,4) x 256. Transposed x tile TX[m][e]
// built from 16 per-e coalesced dword loads (lane=m) -> lane holds e-slices.
// wm a-frags + beta hoisted out of loop. 4 ds_read + 8 mfma per tile/wave.
// ---------------------------------------------------------------------------
extern "C" __global__ __launch_bounds__(256)
void k_apply(const float* __restrict__ X, const float* __restrict__ ws,
             float* __restrict__ out) {
    __shared__ __align__(16) unsigned short tx[2][64 * LDB];
    __shared__ __align__(16) unsigned short wm_s[64 * LDB];

    const int g = blockIdx.y, tid = threadIdx.x;
    const int lane = tid & 63, w = tid >> 6;
    const int l15 = lane & 15, lg = lane >> 4;
    const float* Xg = X + (size_t)g * 64 * HWc;

    {   // stage wm fp32 -> bf16
        const float* Wp = ws + WS_WM + g * 4096;
        const int r = tid >> 2, ch = (tid & 3) << 4;
        const float* p = Wp + r * 64 + ch;
        const f32x4v v0 = *(const f32x4v*)(p);      const f32x4v v1 = *(const f32x4v*)(p + 4);
        const f32x4v v2 = *(const f32x4v*)(p + 8);  const f32x4v v3 = *(const f32x4v*)(p + 12);
        unsigned short* dst = &wm_s[r * LDB + ch];
        *(u32x4*)(dst)     = (u32x4){bfpack2(v0.x,v0.y), bfpack2(v0.z,v0.w),
                                     bfpack2(v1.x,v1.y), bfpack2(v1.z,v1.w)};
        *(u32x4*)(dst + 8) = (u32x4){bfpack2(v2.x,v2.y), bfpack2(v2.z,v2.w),
                                     bfpack2(v3.x,v3.y), bfpack2(v3.z,v3.w)};
    }
    __syncthreads();

    const int CB0 = (w >> 1) << 1, MB0 = (w & 1) << 1;
    short8 afrag[2][2];
    #pragma unroll
    for (int ci = 0; ci < 2; ++ci)
        #pragma unroll
        for (int s = 0; s < 2; ++s)
            afrag[ci][s] = *(const short8*)&wm_s[((CB0 + ci) * 16 + l15) * LDB + 8 * lg + 32 * s];

    float betav[2][4]; size_t crow[2][4];
    #pragma unroll
    for (int ci = 0; ci < 2; ++ci)
        #pragma unroll
        for (int reg = 0; reg < 4; ++reg) {
            const int cl = (CB0 + ci) * 16 + lg * 4 + reg;
            betav[ci][reg] = ws[WS_BETA + g * 64 + cl];
            crow[ci][reg]  = (size_t)(g * 64 + cl) * HWc;
        }
    const int mcol0 = MB0 * 16 + l15, mcol1 = (MB0 + 1) * 16 + l15;

    const int e0 = w * 16;
    float cur[16];
    {
        const int t = blockIdx.x, b = t / 49, hw0 = (t - b * 49) << 6;
        const float* p = Xg + (size_t)b * CHW + (size_t)e0 * HWc + hw0 + lane;
        #pragma unroll
        for (int j = 0; j < 16; ++j) cur[j] = p[(size_t)j * HWc];
    }

    int buf = 0;
    for (int k = 0; k < 16; ++k) {
        const int t = blockIdx.x + GX * k;
        const int b = t / 49, hw0 = (t - b * 49) << 6;

        unsigned short* dst = &tx[buf][lane * LDB + e0];
        *(u32x4*)(dst)     = (u32x4){bfpack2(cur[0],cur[1]),  bfpack2(cur[2],cur[3]),
                                     bfpack2(cur[4],cur[5]),  bfpack2(cur[6],cur[7])};
        *(u32x4*)(dst + 8) = (u32x4){bfpack2(cur[8],cur[9]),  bfpack2(cur[10],cur[11]),
                                     bfpack2(cur[12],cur[13]),bfpack2(cur[14],cur[15])};
        __syncthreads();

        if (k < 15) {                        // prefetch next tile into regs
            const int tn = t + GX, bn = tn / 49, hwn = (tn - bn * 49) << 6;
            const float* p = Xg + (size_t)bn * CHW + (size_t)e0 * HWc + hwn + lane;
            #pragma unroll
            for (int j = 0; j < 16; ++j) cur[j] = p[(size_t)j * HWc];
        }

        f32x4v acc[2][2];
        #pragma unroll
        for (int i = 0; i < 2; ++i)
            #pragma unroll
            for (int j = 0; j < 2; ++j) acc[i][j] = (f32x4v){0.f,0.f,0.f,0.f};

        const unsigned short* T = tx[buf];
        #pragma unroll
        for (int s = 0; s < 2; ++s) {
            const int ko = 8 * lg + 32 * s;
            const short8 b0 = *(const short8*)&T[(MB0 * 16     + l15) * LDB + ko];
            const short8 b1 = *(const short8*)&T[((MB0+1) * 16 + l15) * LDB + ko];
            acc[0][0] = mfma16(afrag[0][s], b0, acc[0][0]);
            acc[0][1] = mfma16(afrag[0][s], b1, acc[0][1]);
            acc[1][0] = mfma16(afrag[1][s], b0, acc[1][0]);
            acc[1][1] = mfma16(afrag[1][s], b1, acc[1][1]);
        }

        float* ob = out + (size_t)b * CHW + hw0;
        #pragma unroll
        for (int ci = 0; ci < 2; ++ci)
            #pragma unroll
            for (int reg = 0; reg < 4; ++reg) {
                ob[crow[ci][reg] + mcol0] = acc[ci][0][reg] + betav[ci][reg];
                ob[crow[ci][reg] + mcol1] = acc[ci][1][reg] + betav[ci][reg];
            }
        buf ^= 1;
    }
}

// ---------------------------------------------------------------------------
extern "C" void kernel_launch(void* const* d_in, const int* in_sizes, int n_in,
                              void* d_out, int out_size, void* d_ws, size_t ws_size,
                              hipStream_t stream) {
    const float* X      = (const float*)d_in[0];
    const float* weight = (const float*)d_in[1];
    const float* bias   = (const float*)d_in[2];
    float* out = (float*)d_out;
    float* ws  = (float*)d_ws;

    hipLaunchKernelGGL(k_zero,  dim3(65),    dim3(256), 0, stream, ws);
    hipLaunchKernelGGL(k_gram,  dim3(GX, 4), dim3(256), 0, stream, X, ws);
    hipLaunchKernelGGL(k_solve, dim3(4),     dim3(256), 0, stream, weight, bias, ws);
    hipLaunchKernelGGL(k_apply, dim3(GX, 4), dim3(256), 0, stream, X, ws, out);
}

// Round 6
// 170.783 us; speedup vs baseline: 2.4353x; 1.0851x over previous
//
#include <hip/hip_runtime.h>
#include <hip/hip_bf16.h>
#include <math.h>

// ---------------------------------------------------------------------------
// IterNorm (64,256,56,56) fp32, g=4 groups of 64 channels.
//  k_gram  : per-block partial Gram (64x64) + channel sums -> slabs (no atomics)
//  k_reduce: sum 196 slabs/group -> G, channel sums -> SUM
//  k_solve : Sigma=G/m-mu mu^T+eps I; Newton-Schulz x5; fold weight/bias/mean
//  k_apply : out = wm_bf16 * x_bf16 + beta via MFMA, transposed-x LDS tile,
//            m-paired D layout -> f32x2 stores
// MFMA 16x16x32_bf16 layouts (HW-verified): A/B-frag lane l: row l&15,
// k=(l>>4)*8+j ; C/D: col=l&15, row=(l>>4)*4+reg.
// Structure notes: 2 tiles per __syncthreads (1 barrier / 128 m), reg-prefetch
// issued right after the barrier so it lands during ~740cy of compute.
// ---------------------------------------------------------------------------

#define EPS_F 1e-5f

using f32x4v = __attribute__((ext_vector_type(4))) float;
using f32x2v = __attribute__((ext_vector_type(2))) float;
using short8 = __attribute__((ext_vector_type(8))) short;
using u32x4  = __attribute__((ext_vector_type(4))) unsigned int;

constexpr int Cc  = 256;
constexpr int HWc = 3136;                 // 56*56
constexpr int CHW = Cc * HWc;             // 802816
constexpr float Mf = 200704.0f;           // 64*3136
constexpr int GX  = 196;                  // 3136 tiles / 196 = 16 tiles/block
constexpr int LDB = 72;                   // bf16 LDS row stride (144 B)

// workspace layout (float offsets)
constexpr int WS_SUM  = 0;                       // 256
constexpr int WS_G    = 256;                     // 4*4096
constexpr int WS_WM   = WS_G + 16384;            // 4*4096
constexpr int WS_BETA = WS_WM + 16384;           // 256
constexpr int WS_SLAB = WS_BETA + 256;           // 784 * 4096 partial Grams
constexpr int WS_SSUM = WS_SLAB + 784 * 4096;    // 784 * 64 partial channel sums

__device__ __forceinline__ unsigned cvtpk(float lo, float hi) {
    // compiles to v_cvt_pk_bf16_f32 (RNE)
    __hip_bfloat162 h = __float22bfloat162_rn(float2{lo, hi});
    unsigned u;
    __builtin_memcpy(&u, &h, 4);
    return u;
}

__device__ __forceinline__ f32x4v mfma16(short8 a, short8 b, f32x4v c) {
    return __builtin_amdgcn_mfma_f32_16x16x32_bf16(a, b, c, 0, 0, 0);
}

// ---------------------------------------------------------------------------
// Kernel 1: partial Gram. grid (196,4) x 256 (4 waves).
// LDS: 2 dbuf x 2 subtiles x [64 c][72 bf16]. Per iteration (2 tiles):
// pack 32 fp32 -> 16 cvt_pk -> 4 ds_write_b128; 1 barrier; 16 ds_read + 16 mfma.
// ---------------------------------------------------------------------------
extern "C" __global__ __launch_bounds__(256)
void k_gram(const float* __restrict__ X, float* __restrict__ ws) {
    __shared__ __align__(16) unsigned short tg[2][2][64 * LDB];
    const int g = blockIdx.y, bx = blockIdx.x, tid = threadIdx.x;
    const int lane = tid & 63, w = tid >> 6;
    const int row = tid >> 2, mo = (tid & 3) << 4;     // load mapping
    const int l15 = lane & 15, lg = lane >> 4;
    const int CBi0 = (w >> 1) << 1, CBj0 = (w & 1) << 1;
    const float* Xg = X + (size_t)g * 64 * HWc;

    f32x4v acc[2][2];
    #pragma unroll
    for (int i = 0; i < 2; ++i)
        #pragma unroll
        for (int j = 0; j < 2; ++j) acc[i][j] = (f32x4v){0.f, 0.f, 0.f, 0.f};
    float csum = 0.0f;

    f32x4v curA[4], curB[4];
    auto loadt = [&](int t, f32x4v* cur) {
        const int b = t / 49, hw0 = (t - b * 49) << 6;
        const float* p = Xg + (size_t)b * CHW + (size_t)row * HWc + hw0 + mo;
        cur[0] = *(const f32x4v*)(p);      cur[1] = *(const f32x4v*)(p + 4);
        cur[2] = *(const f32x4v*)(p + 8);  cur[3] = *(const f32x4v*)(p + 12);
    };
    auto packt = [&](const f32x4v* cur, unsigned short* dstbuf) {
        unsigned pk[8];
        #pragma unroll
        for (int i = 0; i < 4; ++i) {
            csum += (cur[i].x + cur[i].y) + (cur[i].z + cur[i].w);
            pk[2*i]   = cvtpk(cur[i].x, cur[i].y);
            pk[2*i+1] = cvtpk(cur[i].z, cur[i].w);
        }
        unsigned short* dst = dstbuf + row * LDB + mo;
        *(u32x4*)(dst)     = (u32x4){pk[0], pk[1], pk[2], pk[3]};
        *(u32x4*)(dst + 8) = (u32x4){pk[4], pk[5], pk[6], pk[7]};
    };
    auto comp = [&](const unsigned short* T) {
        #pragma unroll
        for (int s = 0; s < 2; ++s) {
            const int ko = 8 * lg + 32 * s;
            const short8 a0 = *(const short8*)&T[(CBi0 * 16      + l15) * LDB + ko];
            const short8 a1 = *(const short8*)&T[((CBi0+1) * 16  + l15) * LDB + ko];
            const short8 b0 = *(const short8*)&T[(CBj0 * 16      + l15) * LDB + ko];
            const short8 b1 = *(const short8*)&T[((CBj0+1) * 16  + l15) * LDB + ko];
            acc[0][0] = mfma16(a0, b0, acc[0][0]);
            acc[0][1] = mfma16(a0, b1, acc[0][1]);
            acc[1][0] = mfma16(a1, b0, acc[1][0]);
            acc[1][1] = mfma16(a1, b1, acc[1][1]);
        }
    };

    loadt(bx, curA);
    loadt(bx + GX, curB);

    int buf = 0;
    for (int kk = 0; kk < 8; ++kk) {
        packt(curA, tg[buf][0]);
        packt(curB, tg[buf][1]);
        __syncthreads();
        if (kk < 7) {                              // prefetch next 2 tiles
            loadt(bx + GX * (2*kk + 2), curA);
            loadt(bx + GX * (2*kk + 3), curB);
        }
        comp(tg[buf][0]);
        comp(tg[buf][1]);
        buf ^= 1;
    }

    // channel-sum partial: 4 lanes share a row
    csum += __shfl_down(csum, 1, 4);
    csum += __shfl_down(csum, 2, 4);
    if ((tid & 3) == 0)
        ws[WS_SSUM + (g * GX + bx) * 64 + row] = csum;

    // partial Gram -> private slab (plain stores, no atomics)
    float* Gp = ws + WS_SLAB + (size_t)(g * GX + bx) * 4096;
    #pragma unroll
    for (int ci = 0; ci < 2; ++ci)
        #pragma unroll
        for (int cj = 0; cj < 2; ++cj)
            #pragma unroll
            for (int reg = 0; reg < 4; ++reg) {
                const int r = (CBi0 + ci) * 16 + lg * 4 + reg;
                const int c = (CBj0 + cj) * 16 + l15;
                Gp[r * 64 + c] = acc[ci][cj][reg];
            }
}

// ---------------------------------------------------------------------------
// Kernel 1b: reduce slabs. grid (16,4) x 256. Block (chunk,g) sums 256 cells
// over 196 partials (coalesced 1KB streams, 4-way ILP). chunk 0 also reduces
// the channel sums.
// ---------------------------------------------------------------------------
extern "C" __global__ __launch_bounds__(256)
void k_reduce(float* __restrict__ ws) {
    const int g = blockIdx.y, chunk = blockIdx.x, tid = threadIdx.x;
    const int cell = chunk * 256 + tid;
    const float* p = ws + WS_SLAB + (size_t)g * GX * 4096 + cell;
    float s0 = 0.f, s1 = 0.f, s2 = 0.f, s3 = 0.f;
    #pragma unroll 7
    for (int s4 = 0; s4 < 49; ++s4) {
        s0 += p[0];
        s1 += p[4096];
        s2 += p[2 * 4096];
        s3 += p[3 * 4096];
        p += 4 * 4096;
    }
    ws[WS_G + g * 4096 + cell] = (s0 + s1) + (s2 + s3);

    if (chunk == 0 && tid < 64) {
        const float* q = ws + WS_SSUM + (size_t)g * GX * 64 + tid;
        float a0 = 0.f, a1 = 0.f, a2 = 0.f, a3 = 0.f;
        #pragma unroll 7
        for (int s4 = 0; s4 < 49; ++s4) {
            a0 += q[0];
            a1 += q[64];
            a2 += q[128];
            a3 += q[192];
            q += 256;
        }
        ws[WS_SUM + g * 64 + tid] = (a0 + a1) + (a2 + a3);
    }
}

// ---------------------------------------------------------------------------
// Kernel 2: Newton-Schulz, fp32, 4 blocks x 256. Commuting form:
// M0=Sigma_N; per iter: W=1.5I-0.5M; P<-P*W; M<-(M*W)*W (skip M on last).
// ---------------------------------------------------------------------------
__device__ __forceinline__
void mm64s(float* C, const float* A, const float* B, int r0, int c0) {
    f32x4v s[4] = {{0,0,0,0},{0,0,0,0},{0,0,0,0},{0,0,0,0}};
    #pragma unroll 4
    for (int kk = 0; kk < 16; ++kk) {
        const f32x4v b0 = *(const f32x4v*)&B[(4*kk + 0) * 68 + c0];
        const f32x4v b1 = *(const f32x4v*)&B[(4*kk + 1) * 68 + c0];
        const f32x4v b2 = *(const f32x4v*)&B[(4*kk + 2) * 68 + c0];
        const f32x4v b3 = *(const f32x4v*)&B[(4*kk + 3) * 68 + c0];
        #pragma unroll
        for (int i = 0; i < 4; ++i) {
            const f32x4v a = *(const f32x4v*)&A[(r0 + i) * 68 + 4 * kk];
            s[i] += a.x * b0 + a.y * b1 + a.z * b2 + a.w * b3;
        }
    }
    __syncthreads();
    #pragma unroll
    for (int i = 0; i < 4; ++i) *(f32x4v*)&C[(r0 + i) * 68 + c0] = s[i];
    __syncthreads();
}

extern "C" __global__ __launch_bounds__(256)
void k_solve(const float* __restrict__ weight, const float* __restrict__ bias,
             float* __restrict__ ws) {
    __shared__ __align__(16) float M [64 * 68];
    __shared__ __align__(16) float P [64 * 68];
    __shared__ __align__(16) float W [64 * 68];
    __shared__ __align__(16) float T1[64 * 68];
    __shared__ __align__(16) float mean_s[64];
    __shared__ float red;

    const int g = blockIdx.x, tid = threadIdx.x;
    const int r = tid >> 2, ch = (tid & 3) << 4;          // elementwise mapping
    const int r0 = (tid >> 4) << 2, c0 = (tid & 15) << 2; // mm mapping

    if (tid < 64) mean_s[tid] = ws[WS_SUM + g * 64 + tid] * (1.0f / Mf);
    __syncthreads();

    const float* Gp = ws + WS_G + g * 4096;
    const float mr = mean_s[r];
    #pragma unroll
    for (int j4 = 0; j4 < 4; ++j4) {
        const int c = ch + 4 * j4;
        const f32x4v gv = *(const f32x4v*)&Gp[r * 64 + c];
        const f32x4v mc = *(const f32x4v*)&mean_s[c];
        f32x4v sv, pv = {0,0,0,0};
        #pragma unroll
        for (int j = 0; j < 4; ++j) {
            float v = gv[j] * (1.0f / Mf) - mr * mc[j];
            if (c + j == r) { v += EPS_F; pv[j] = 1.0f; }
            sv[j] = v;
        }
        *(f32x4v*)&M[r * 68 + c] = sv;
        *(f32x4v*)&P[r * 68 + c] = pv;
    }
    __syncthreads();

    if (tid == 0) {
        float tr = 0.f;
        #pragma unroll
        for (int i = 0; i < 64; ++i) tr += M[i * 68 + i];
        red = 1.0f / tr;
    }
    __syncthreads();
    const float rtr = red;
    #pragma unroll
    for (int j4 = 0; j4 < 4; ++j4) {
        const int c = ch + 4 * j4;
        *(f32x4v*)&M[r * 68 + c] = *(const f32x4v*)&M[r * 68 + c] * rtr;
    }
    __syncthreads();

    for (int t = 0; t < 5; ++t) {
        #pragma unroll
        for (int j4 = 0; j4 < 4; ++j4) {     // W = 1.5I - 0.5M
            const int c = ch + 4 * j4;
            f32x4v mv = *(const f32x4v*)&M[r * 68 + c];
            f32x4v wv = -0.5f * mv;
            #pragma unroll
            for (int j = 0; j < 4; ++j) if (c + j == r) wv[j] += 1.5f;
            *(f32x4v*)&W[r * 68 + c] = wv;
        }
        __syncthreads();
        mm64s(P, P, W, r0, c0);              // P <- P*W (alias-safe)
        if (t < 4) {
            mm64s(T1, M, W, r0, c0);         // T1 = M*W
            mm64s(M, T1, W, r0, c0);         // M  = T1*W
        }
    }

    const float srtr = sqrtf(rtr);
    const float wr = weight[g * 64 + r];
    float* Wp = ws + WS_WM + g * 4096;
    float part = 0.0f;
    #pragma unroll
    for (int j4 = 0; j4 < 4; ++j4) {
        const int c = ch + 4 * j4;
        const f32x4v pv = *(const f32x4v*)&P[r * 68 + c] * srtr;
        *(f32x4v*)&Wp[r * 64 + c] = pv * wr;
        const f32x4v mc = *(const f32x4v*)&mean_s[c];
        part += pv.x * mc.x + pv.y * mc.y + pv.z * mc.z + pv.w * mc.w;
    }
    part += __shfl_down(part, 1, 4);
    part += __shfl_down(part, 2, 4);
    if ((tid & 3) == 0)
        ws[WS_BETA + g * 64 + r] = bias[g * 64 + r] - wr * part;
}

// ---------------------------------------------------------------------------
// Kernel 3: apply. grid (196,4) x 256. TX row r <-> global m permuted so the
// wave's two m-blocks are interleaved (m = 2*l15 + blk): D cols pair adjacent
// m -> f32x2 stores (8 insts, 128B segments). 2 tiles per barrier.
// ---------------------------------------------------------------------------
extern "C" __global__ __launch_bounds__(256)
void k_apply(const float* __restrict__ X, const float* __restrict__ ws,
             float* __restrict__ out) {
    __shared__ __align__(16) unsigned short tx[2][2][64 * LDB];
    __shared__ __align__(16) unsigned short wm_s[64 * LDB];

    const int g = blockIdx.y, bx = blockIdx.x, tid = threadIdx.x;
    const int lane = tid & 63, w = tid >> 6;
    const int l15 = lane & 15, lg = lane >> 4;
    const float* Xg = X + (size_t)g * 64 * HWc;

    {   // stage wm fp32 -> bf16
        const float* Wp = ws + WS_WM + g * 4096;
        const int r = tid >> 2, ch = (tid & 3) << 4;
        const float* p = Wp + r * 64 + ch;
        const f32x4v v0 = *(const f32x4v*)(p);      const f32x4v v1 = *(const f32x4v*)(p + 4);
        const f32x4v v2 = *(const f32x4v*)(p + 8);  const f32x4v v3 = *(const f32x4v*)(p + 12);
        unsigned short* dst = &wm_s[r * LDB + ch];
        *(u32x4*)(dst)     = (u32x4){cvtpk(v0.x,v0.y), cvtpk(v0.z,v0.w),
                                     cvtpk(v1.x,v1.y), cvtpk(v1.z,v1.w)};
        *(u32x4*)(dst + 8) = (u32x4){cvtpk(v2.x,v2.y), cvtpk(v2.z,v2.w),
                                     cvtpk(v3.x,v3.y), cvtpk(v3.z,v3.w)};
    }
    __syncthreads();

    const int CB0 = (w >> 1) << 1, MB0 = (w & 1) << 1;
    short8 afrag[2][2];
    #pragma unroll
    for (int ci = 0; ci < 2; ++ci)
        #pragma unroll
        for (int s = 0; s < 2; ++s)
            afrag[ci][s] = *(const short8*)&wm_s[((CB0 + ci) * 16 + l15) * LDB + 8 * lg + 32 * s];

    float betav[2][4]; int crow[2][4];
    #pragma unroll
    for (int ci = 0; ci < 2; ++ci)
        #pragma unroll
        for (int reg = 0; reg < 4; ++reg) {
            const int cl = (CB0 + ci) * 16 + lg * 4 + reg;
            betav[ci][reg] = ws[WS_BETA + g * 64 + cl];
            crow[ci][reg]  = (g * 64 + cl) * HWc;
        }
    // stage-row permutation: lane (= global m within tile) -> TX row
    const int rT   = 32 * (lane >> 5) + 16 * (lane & 1) + ((lane & 31) >> 1);
    const int mcb  = 32 * (w & 1) + 2 * l15;            // store col base
    const int e0 = w * 16;

    float curA[16], curB[16];
    auto loadt = [&](int t, float* cur) {
        const int b = t / 49, hw0 = (t - b * 49) << 6;
        const float* p = Xg + (size_t)b * CHW + (size_t)e0 * HWc + hw0 + lane;
        #pragma unroll
        for (int j = 0; j < 16; ++j) cur[j] = p[(size_t)j * HWc];
    };
    auto packt = [&](const float* cur, unsigned short* dstbuf) {
        unsigned short* dst = dstbuf + rT * LDB + e0;
        *(u32x4*)(dst)     = (u32x4){cvtpk(cur[0],cur[1]),   cvtpk(cur[2],cur[3]),
                                     cvtpk(cur[4],cur[5]),   cvtpk(cur[6],cur[7])};
        *(u32x4*)(dst + 8) = (u32x4){cvtpk(cur[8],cur[9]),   cvtpk(cur[10],cur[11]),
                                     cvtpk(cur[12],cur[13]), cvtpk(cur[14],cur[15])};
    };
    auto compst = [&](const unsigned short* T, int t) {
        f32x4v acc[2][2];
        #pragma unroll
        for (int i = 0; i < 2; ++i)
            #pragma unroll
            for (int j = 0; j < 2; ++j) acc[i][j] = (f32x4v){0.f,0.f,0.f,0.f};
        #pragma unroll
        for (int s = 0; s < 2; ++s) {
            const int ko = 8 * lg + 32 * s;
            const short8 b0 = *(const short8*)&T[(MB0 * 16     + l15) * LDB + ko];
            const short8 b1 = *(const short8*)&T[((MB0+1) * 16 + l15) * LDB + ko];
            acc[0][0] = mfma16(afrag[0][s], b0, acc[0][0]);
            acc[0][1] = mfma16(afrag[0][s], b1, acc[0][1]);
            acc[1][0] = mfma16(afrag[1][s], b0, acc[1][0]);
            acc[1][1] = mfma16(afrag[1][s], b1, acc[1][1]);
        }
        const int b = t / 49, hw0 = (t - b * 49) << 6;
        float* ob = out + (size_t)b * CHW + hw0 + mcb;
        #pragma unroll
        for (int ci = 0; ci < 2; ++ci)
            #pragma unroll
            for (int reg = 0; reg < 4; ++reg) {
                const float bt = betav[ci][reg];
                *(f32x2v*)(ob + crow[ci][reg]) =
                    (f32x2v){acc[ci][0][reg] + bt, acc[ci][1][reg] + bt};
            }
    };

    loadt(bx, curA);
    loadt(bx + GX, curB);

    int buf = 0;
    for (int kk = 0; kk < 8; ++kk) {
        packt(curA, tx[buf][0]);
        packt(curB, tx[buf][1]);
        __syncthreads();
        if (kk < 7) {
            loadt(bx + GX * (2*kk + 2), curA);
            loadt(bx + GX * (2*kk + 3), curB);
        }
        compst(tx[buf][0], bx + GX * (2*kk));
        compst(tx[buf][1], bx + GX * (2*kk + 1));
        buf ^= 1;
    }
}

// ---------------------------------------------------------------------------
extern "C" void kernel_launch(void* const* d_in, const int* in_sizes, int n_in,
                              void* d_out, int out_size, void* d_ws, size_t ws_size,
                              hipStream_t stream) {
    const float* X      = (const float*)d_in[0];
    const float* weight = (const float*)d_in[1];
    const float* bias   = (const float*)d_in[2];
    float* out = (float*)d_out;
    float* ws  = (float*)d_ws;

    hipLaunchKernelGGL(k_gram,   dim3(GX, 4), dim3(256), 0, stream, X, ws);
    hipLaunchKernelGGL(k_reduce, dim3(16, 4), dim3(256), 0, stream, ws);
    hipLaunchKernelGGL(k_solve,  dim3(4),     dim3(256), 0, stream, weight, bias, ws);
    hipLaunchKernelGGL(k_apply,  dim3(GX, 4), dim3(256), 0, stream, X, ws, out);
}

// Round 7
// 153.539 us; speedup vs baseline: 2.7088x; 1.1123x over previous
//
#include <hip/hip_runtime.h>
#include <hip/hip_bf16.h>
#include <math.h>

// ---------------------------------------------------------------------------
// IterNorm (64,256,56,56) fp32, g=4 groups of 64 channels.
//  k_gram  : per-block partial Gram (64x64) + channel sums -> slabs (no atomics)
//  k_reduce: sum 196 slabs/group -> G, channel sums -> SUM
//  k_solve : Sigma=G/m-mu mu^T+eps I; Newton-Schulz x5; fold weight/bias/mean
//  k_apply : out = wm_bf16 * x_bf16 + beta via MFMA, transposed-x LDS tile,
//            m-paired D layout -> NONTEMPORAL f32x2 stores (out is write-once:
//            keep it out of L3 so X (205MB) stays Infinity-Cache-resident
//            across replays -> both X readers become L3-bound, not HBM-bound)
// MFMA 16x16x32_bf16 layouts (HW-verified): A/B-frag lane l: row l&15,
// k=(l>>4)*8+j ; C/D: col=l&15, row=(l>>4)*4+reg.
// ---------------------------------------------------------------------------

#define EPS_F 1e-5f

using f32x4v = __attribute__((ext_vector_type(4))) float;
using f32x2v = __attribute__((ext_vector_type(2))) float;
using short8 = __attribute__((ext_vector_type(8))) short;
using u32x4  = __attribute__((ext_vector_type(4))) unsigned int;

constexpr int Cc  = 256;
constexpr int HWc = 3136;                 // 56*56
constexpr int CHW = Cc * HWc;             // 802816
constexpr float Mf = 200704.0f;           // 64*3136
constexpr int GX  = 196;                  // 3136 tiles / 196 = 16 tiles/block
constexpr int LDB = 72;                   // bf16 LDS row stride (144 B)

// workspace layout (float offsets)
constexpr int WS_SUM  = 0;                       // 256
constexpr int WS_G    = 256;                     // 4*4096
constexpr int WS_WM   = WS_G + 16384;            // 4*4096
constexpr int WS_BETA = WS_WM + 16384;           // 256
constexpr int WS_SLAB = WS_BETA + 256;           // 784 * 4096 partial Grams
constexpr int WS_SSUM = WS_SLAB + 784 * 4096;    // 784 * 64 partial channel sums

__device__ __forceinline__ unsigned cvtpk(float lo, float hi) {
    // compiles to v_cvt_pk_bf16_f32 (RNE)
    __hip_bfloat162 h = __float22bfloat162_rn(float2{lo, hi});
    unsigned u;
    __builtin_memcpy(&u, &h, 4);
    return u;
}

__device__ __forceinline__ f32x4v mfma16(short8 a, short8 b, f32x4v c) {
    return __builtin_amdgcn_mfma_f32_16x16x32_bf16(a, b, c, 0, 0, 0);
}

// ---------------------------------------------------------------------------
// Kernel 1: partial Gram. grid (196,4) x 256 (4 waves). LDS 36.9KB -> 4 blk/CU.
// ---------------------------------------------------------------------------
extern "C" __global__ __launch_bounds__(256, 4)
void k_gram(const float* __restrict__ X, float* __restrict__ ws) {
    __shared__ __align__(16) unsigned short tg[2][2][64 * LDB];
    const int g = blockIdx.y, bx = blockIdx.x, tid = threadIdx.x;
    const int lane = tid & 63, w = tid >> 6;
    const int row = tid >> 2, mo = (tid & 3) << 4;     // load mapping
    const int l15 = lane & 15, lg = lane >> 4;
    const int CBi0 = (w >> 1) << 1, CBj0 = (w & 1) << 1;
    const float* Xg = X + (size_t)g * 64 * HWc;

    f32x4v acc[2][2];
    #pragma unroll
    for (int i = 0; i < 2; ++i)
        #pragma unroll
        for (int j = 0; j < 2; ++j) acc[i][j] = (f32x4v){0.f, 0.f, 0.f, 0.f};
    float csum = 0.0f;

    f32x4v curA[4], curB[4];
    auto loadt = [&](int t, f32x4v* cur) {
        const int b = t / 49, hw0 = (t - b * 49) << 6;
        const float* p = Xg + (size_t)b * CHW + (size_t)row * HWc + hw0 + mo;
        cur[0] = *(const f32x4v*)(p);      cur[1] = *(const f32x4v*)(p + 4);
        cur[2] = *(const f32x4v*)(p + 8);  cur[3] = *(const f32x4v*)(p + 12);
    };
    auto packt = [&](const f32x4v* cur, unsigned short* dstbuf) {
        unsigned pk[8];
        #pragma unroll
        for (int i = 0; i < 4; ++i) {
            csum += (cur[i].x + cur[i].y) + (cur[i].z + cur[i].w);
            pk[2*i]   = cvtpk(cur[i].x, cur[i].y);
            pk[2*i+1] = cvtpk(cur[i].z, cur[i].w);
        }
        unsigned short* dst = dstbuf + row * LDB + mo;
        *(u32x4*)(dst)     = (u32x4){pk[0], pk[1], pk[2], pk[3]};
        *(u32x4*)(dst + 8) = (u32x4){pk[4], pk[5], pk[6], pk[7]};
    };
    auto comp = [&](const unsigned short* T) {
        #pragma unroll
        for (int s = 0; s < 2; ++s) {
            const int ko = 8 * lg + 32 * s;
            const short8 a0 = *(const short8*)&T[(CBi0 * 16      + l15) * LDB + ko];
            const short8 a1 = *(const short8*)&T[((CBi0+1) * 16  + l15) * LDB + ko];
            const short8 b0 = *(const short8*)&T[(CBj0 * 16      + l15) * LDB + ko];
            const short8 b1 = *(const short8*)&T[((CBj0+1) * 16  + l15) * LDB + ko];
            acc[0][0] = mfma16(a0, b0, acc[0][0]);
            acc[0][1] = mfma16(a0, b1, acc[0][1]);
            acc[1][0] = mfma16(a1, b0, acc[1][0]);
            acc[1][1] = mfma16(a1, b1, acc[1][1]);
        }
    };

    loadt(bx, curA);
    loadt(bx + GX, curB);

    int buf = 0;
    for (int kk = 0; kk < 8; ++kk) {
        packt(curA, tg[buf][0]);
        packt(curB, tg[buf][1]);
        __syncthreads();
        if (kk < 7) {                              // prefetch next 2 tiles
            loadt(bx + GX * (2*kk + 2), curA);
            loadt(bx + GX * (2*kk + 3), curB);
        }
        comp(tg[buf][0]);
        comp(tg[buf][1]);
        buf ^= 1;
    }

    // channel-sum partial: 4 lanes share a row
    csum += __shfl_down(csum, 1, 4);
    csum += __shfl_down(csum, 2, 4);
    if ((tid & 3) == 0)
        ws[WS_SSUM + (g * GX + bx) * 64 + row] = csum;

    // partial Gram -> private slab (plain stores, no atomics)
    float* Gp = ws + WS_SLAB + (size_t)(g * GX + bx) * 4096;
    #pragma unroll
    for (int ci = 0; ci < 2; ++ci)
        #pragma unroll
        for (int cj = 0; cj < 2; ++cj)
            #pragma unroll
            for (int reg = 0; reg < 4; ++reg) {
                const int r = (CBi0 + ci) * 16 + lg * 4 + reg;
                const int c = (CBj0 + cj) * 16 + l15;
                Gp[r * 64 + c] = acc[ci][cj][reg];
            }
}

// ---------------------------------------------------------------------------
// Kernel 1b: reduce slabs. grid (16,4) x 256.
// ---------------------------------------------------------------------------
extern "C" __global__ __launch_bounds__(256)
void k_reduce(float* __restrict__ ws) {
    const int g = blockIdx.y, chunk = blockIdx.x, tid = threadIdx.x;
    const int cell = chunk * 256 + tid;
    const float* p = ws + WS_SLAB + (size_t)g * GX * 4096 + cell;
    float s0 = 0.f, s1 = 0.f, s2 = 0.f, s3 = 0.f;
    #pragma unroll 7
    for (int s4 = 0; s4 < 49; ++s4) {
        s0 += p[0];
        s1 += p[4096];
        s2 += p[2 * 4096];
        s3 += p[3 * 4096];
        p += 4 * 4096;
    }
    ws[WS_G + g * 4096 + cell] = (s0 + s1) + (s2 + s3);

    if (chunk == 0 && tid < 64) {
        const float* q = ws + WS_SSUM + (size_t)g * GX * 64 + tid;
        float a0 = 0.f, a1 = 0.f, a2 = 0.f, a3 = 0.f;
        #pragma unroll 7
        for (int s4 = 0; s4 < 49; ++s4) {
            a0 += q[0];
            a1 += q[64];
            a2 += q[128];
            a3 += q[192];
            q += 256;
        }
        ws[WS_SUM + g * 64 + tid] = (a0 + a1) + (a2 + a3);
    }
}

// ---------------------------------------------------------------------------
// Kernel 2: Newton-Schulz, fp32, 4 blocks x 256. Commuting form:
// M0=Sigma_N; per iter: W=1.5I-0.5M; P<-P*W; M<-(M*W)*W (skip M on last).
// ---------------------------------------------------------------------------
__device__ __forceinline__
void mm64s(float* C, const float* A, const float* B, int r0, int c0) {
    f32x4v s[4] = {{0,0,0,0},{0,0,0,0},{0,0,0,0},{0,0,0,0}};
    #pragma unroll 4
    for (int kk = 0; kk < 16; ++kk) {
        const f32x4v b0 = *(const f32x4v*)&B[(4*kk + 0) * 68 + c0];
        const f32x4v b1 = *(const f32x4v*)&B[(4*kk + 1) * 68 + c0];
        const f32x4v b2 = *(const f32x4v*)&B[(4*kk + 2) * 68 + c0];
        const f32x4v b3 = *(const f32x4v*)&B[(4*kk + 3) * 68 + c0];
        #pragma unroll
        for (int i = 0; i < 4; ++i) {
            const f32x4v a = *(const f32x4v*)&A[(r0 + i) * 68 + 4 * kk];
            s[i] += a.x * b0 + a.y * b1 + a.z * b2 + a.w * b3;
        }
    }
    __syncthreads();
    #pragma unroll
    for (int i = 0; i < 4; ++i) *(f32x4v*)&C[(r0 + i) * 68 + c0] = s[i];
    __syncthreads();
}

extern "C" __global__ __launch_bounds__(256)
void k_solve(const float* __restrict__ weight, const float* __restrict__ bias,
             float* __restrict__ ws) {
    __shared__ __align__(16) float M [64 * 68];
    __shared__ __align__(16) float P [64 * 68];
    __shared__ __align__(16) float W [64 * 68];
    __shared__ __align__(16) float T1[64 * 68];
    __shared__ __align__(16) float mean_s[64];
    __shared__ float red;

    const int g = blockIdx.x, tid = threadIdx.x;
    const int r = tid >> 2, ch = (tid & 3) << 4;          // elementwise mapping
    const int r0 = (tid >> 4) << 2, c0 = (tid & 15) << 2; // mm mapping

    if (tid < 64) mean_s[tid] = ws[WS_SUM + g * 64 + tid] * (1.0f / Mf);
    __syncthreads();

    const float* Gp = ws + WS_G + g * 4096;
    const float mr = mean_s[r];
    #pragma unroll
    for (int j4 = 0; j4 < 4; ++j4) {
        const int c = ch + 4 * j4;
        const f32x4v gv = *(const f32x4v*)&Gp[r * 64 + c];
        const f32x4v mc = *(const f32x4v*)&mean_s[c];
        f32x4v sv, pv = {0,0,0,0};
        #pragma unroll
        for (int j = 0; j < 4; ++j) {
            float v = gv[j] * (1.0f / Mf) - mr * mc[j];
            if (c + j == r) { v += EPS_F; pv[j] = 1.0f; }
            sv[j] = v;
        }
        *(f32x4v*)&M[r * 68 + c] = sv;
        *(f32x4v*)&P[r * 68 + c] = pv;
    }
    __syncthreads();

    if (tid == 0) {
        float tr = 0.f;
        #pragma unroll
        for (int i = 0; i < 64; ++i) tr += M[i * 68 + i];
        red = 1.0f / tr;
    }
    __syncthreads();
    const float rtr = red;
    #pragma unroll
    for (int j4 = 0; j4 < 4; ++j4) {
        const int c = ch + 4 * j4;
        *(f32x4v*)&M[r * 68 + c] = *(const f32x4v*)&M[r * 68 + c] * rtr;
    }
    __syncthreads();

    for (int t = 0; t < 5; ++t) {
        #pragma unroll
        for (int j4 = 0; j4 < 4; ++j4) {     // W = 1.5I - 0.5M
            const int c = ch + 4 * j4;
            f32x4v mv = *(const f32x4v*)&M[r * 68 + c];
            f32x4v wv = -0.5f * mv;
            #pragma unroll
            for (int j = 0; j < 4; ++j) if (c + j == r) wv[j] += 1.5f;
            *(f32x4v*)&W[r * 68 + c] = wv;
        }
        __syncthreads();
        mm64s(P, P, W, r0, c0);              // P <- P*W (alias-safe)
        if (t < 4) {
            mm64s(T1, M, W, r0, c0);         // T1 = M*W
            mm64s(M, T1, W, r0, c0);         // M  = T1*W
        }
    }

    const float srtr = sqrtf(rtr);
    const float wr = weight[g * 64 + r];
    float* Wp = ws + WS_WM + g * 4096;
    float part = 0.0f;
    #pragma unroll
    for (int j4 = 0; j4 < 4; ++j4) {
        const int c = ch + 4 * j4;
        const f32x4v pv = *(const f32x4v*)&P[r * 68 + c] * srtr;
        *(f32x4v*)&Wp[r * 64 + c] = pv * wr;
        const f32x4v mc = *(const f32x4v*)&mean_s[c];
        part += pv.x * mc.x + pv.y * mc.y + pv.z * mc.z + pv.w * mc.w;
    }
    part += __shfl_down(part, 1, 4);
    part += __shfl_down(part, 2, 4);
    if ((tid & 3) == 0)
        ws[WS_BETA + g * 64 + r] = bias[g * 64 + r] - wr * part;
}

// ---------------------------------------------------------------------------
// Kernel 3: apply. grid (196,4) x 256. wm staged into tx[0][0] (aliased; frags
// move to regs before the main loop) -> LDS 36.9KB -> 4 blocks/CU. Out stores
// are NONTEMPORAL so the 205MB stream never evicts X from Infinity Cache.
// ---------------------------------------------------------------------------
extern "C" __global__ __launch_bounds__(256, 4)
void k_apply(const float* __restrict__ X, const float* __restrict__ ws,
             float* __restrict__ out) {
    __shared__ __align__(16) unsigned short tx[2][2][64 * LDB];
    __shared__ __align__(16) float beta_sh[64];

    const int g = blockIdx.y, bx = blockIdx.x, tid = threadIdx.x;
    const int lane = tid & 63, w = tid >> 6;
    const int l15 = lane & 15, lg = lane >> 4;
    const float* Xg = X + (size_t)g * 64 * HWc;

    {   // stage wm fp32 -> bf16 into tx[0][0] (reused as x-tile later)
        unsigned short* wm_s = &tx[0][0][0];
        const float* Wp = ws + WS_WM + g * 4096;
        const int r = tid >> 2, ch = (tid & 3) << 4;
        const float* p = Wp + r * 64 + ch;
        const f32x4v v0 = *(const f32x4v*)(p);      const f32x4v v1 = *(const f32x4v*)(p + 4);
        const f32x4v v2 = *(const f32x4v*)(p + 8);  const f32x4v v3 = *(const f32x4v*)(p + 12);
        unsigned short* dst = &wm_s[r * LDB + ch];
        *(u32x4*)(dst)     = (u32x4){cvtpk(v0.x,v0.y), cvtpk(v0.z,v0.w),
                                     cvtpk(v1.x,v1.y), cvtpk(v1.z,v1.w)};
        *(u32x4*)(dst + 8) = (u32x4){cvtpk(v2.x,v2.y), cvtpk(v2.z,v2.w),
                                     cvtpk(v3.x,v3.y), cvtpk(v3.z,v3.w)};
        if (tid < 64) beta_sh[tid] = ws[WS_BETA + g * 64 + tid];
    }
    __syncthreads();

    const int CB0 = (w >> 1) << 1, MB0 = (w & 1) << 1;
    short8 afrag[2][2];
    {
        const unsigned short* wm_s = &tx[0][0][0];
        #pragma unroll
        for (int ci = 0; ci < 2; ++ci)
            #pragma unroll
            for (int s = 0; s < 2; ++s)
                afrag[ci][s] = *(const short8*)&wm_s[((CB0 + ci) * 16 + l15) * LDB + 8 * lg + 32 * s];
    }

    float betav[2][4]; int crow[2][4];
    #pragma unroll
    for (int ci = 0; ci < 2; ++ci)
        #pragma unroll
        for (int reg = 0; reg < 4; ++reg) {
            const int cl = (CB0 + ci) * 16 + lg * 4 + reg;
            betav[ci][reg] = beta_sh[cl];
            crow[ci][reg]  = (g * 64 + cl) * HWc;
        }
    __syncthreads();   // all frag/beta reads done before tx[0][0] is overwritten

    // stage-row permutation: lane (= global m within tile) -> TX row
    const int rT   = 32 * (lane >> 5) + 16 * (lane & 1) + ((lane & 31) >> 1);
    const int mcb  = 32 * (w & 1) + 2 * l15;            // store col base
    const int e0 = w * 16;

    float curA[16], curB[16];
    auto loadt = [&](int t, float* cur) {
        const int b = t / 49, hw0 = (t - b * 49) << 6;
        const float* p = Xg + (size_t)b * CHW + (size_t)e0 * HWc + hw0 + lane;
        #pragma unroll
        for (int j = 0; j < 16; ++j) cur[j] = p[(size_t)j * HWc];
    };
    auto packt = [&](const float* cur, unsigned short* dstbuf) {
        unsigned short* dst = dstbuf + rT * LDB + e0;
        *(u32x4*)(dst)     = (u32x4){cvtpk(cur[0],cur[1]),   cvtpk(cur[2],cur[3]),
                                     cvtpk(cur[4],cur[5]),   cvtpk(cur[6],cur[7])};
        *(u32x4*)(dst + 8) = (u32x4){cvtpk(cur[8],cur[9]),   cvtpk(cur[10],cur[11]),
                                     cvtpk(cur[12],cur[13]), cvtpk(cur[14],cur[15])};
    };
    auto compst = [&](const unsigned short* T, int t) {
        f32x4v acc[2][2];
        #pragma unroll
        for (int i = 0; i < 2; ++i)
            #pragma unroll
            for (int j = 0; j < 2; ++j) acc[i][j] = (f32x4v){0.f,0.f,0.f,0.f};
        #pragma unroll
        for (int s = 0; s < 2; ++s) {
            const int ko = 8 * lg + 32 * s;
            const short8 b0 = *(const short8*)&T[(MB0 * 16     + l15) * LDB + ko];
            const short8 b1 = *(const short8*)&T[((MB0+1) * 16 + l15) * LDB + ko];
            acc[0][0] = mfma16(afrag[0][s], b0, acc[0][0]);
            acc[0][1] = mfma16(afrag[0][s], b1, acc[0][1]);
            acc[1][0] = mfma16(afrag[1][s], b0, acc[1][0]);
            acc[1][1] = mfma16(afrag[1][s], b1, acc[1][1]);
        }
        const int b = t / 49, hw0 = (t - b * 49) << 6;
        float* ob = out + (size_t)b * CHW + hw0 + mcb;
        #pragma unroll
        for (int ci = 0; ci < 2; ++ci)
            #pragma unroll
            for (int reg = 0; reg < 4; ++reg) {
                const float bt = betav[ci][reg];
                const f32x2v v = {acc[ci][0][reg] + bt, acc[ci][1][reg] + bt};
                __builtin_nontemporal_store(v, (f32x2v*)(ob + crow[ci][reg]));
            }
    };

    loadt(bx, curA);
    loadt(bx + GX, curB);

    int buf = 0;
    for (int kk = 0; kk < 8; ++kk) {
        packt(curA, tx[buf][0]);
        packt(curB, tx[buf][1]);
        __syncthreads();
        if (kk < 7) {
            loadt(bx + GX * (2*kk + 2), curA);
            loadt(bx + GX * (2*kk + 3), curB);
        }
        compst(tx[buf][0], bx + GX * (2*kk));
        compst(tx[buf][1], bx + GX * (2*kk + 1));
        buf ^= 1;
    }
}

// ---------------------------------------------------------------------------
extern "C" void kernel_launch(void* const* d_in, const int* in_sizes, int n_in,
                              void* d_out, int out_size, void* d_ws, size_t ws_size,
                              hipStream_t stream) {
    const float* X      = (const float*)d_in[0];
    const float* weight = (const float*)d_in[1];
    const float* bias   = (const float*)d_in[2];
    float* out = (float*)d_out;
    float* ws  = (float*)d_ws;

    hipLaunchKernelGGL(k_gram,   dim3(GX, 4), dim3(256), 0, stream, X, ws);
    hipLaunchKernelGGL(k_reduce, dim3(16, 4), dim3(256), 0, stream, ws);
    hipLaunchKernelGGL(k_solve,  dim3(4),     dim3(256), 0, stream, weight, bias, ws);
    hipLaunchKernelGGL(k_apply,  dim3(GX, 4), dim3(256), 0, stream, X, ws, out);
}

// Round 8
// 133.435 us; speedup vs baseline: 3.1169x; 1.1507x over previous
//
#include <hip/hip_runtime.h>
#include <hip/hip_bf16.h>
#include <math.h>

// ---------------------------------------------------------------------------
// IterNorm (64,256,56,56) fp32, g=4 groups of 64 channels.
//  k_gram  : per-block partial Gram (64x64) + channel sums -> slabs (no atomics)
//  k_reduce: sum 196 slabs/group -> G, channel sums -> SUM (256 blocks)
//  k_solve : Sigma=G/m-mu mu^T+eps I; Newton-Schulz x5 via MFMA with hi/lo
//            bf16 split (Ah*Bh + Al*Bh + Ah*Bl, fp32 accum ~2^-16 rel err);
//            all NS matrices are symmetric commuting polys of Sigma_N, so
//            gram-style D=A*B^T == A*B. fold weight/bias/mean -> wm/beta.
//  k_apply : out = wm_bf16 * x_bf16 + beta via MFMA, transposed-x LDS tile,
//            m-paired D layout -> NONTEMPORAL f32x2 stores (write-once out
//            stays out of L3 so X stays Infinity-Cache-resident)
// MFMA 16x16x32_bf16 layouts (HW-verified): A/B-frag lane l: row l&15,
// k=(l>>4)*8+j ; C/D: col=l&15, row=(l>>4)*4+reg.
// ---------------------------------------------------------------------------

#define EPS_F 1e-5f

using f32x4v = __attribute__((ext_vector_type(4))) float;
using f32x2v = __attribute__((ext_vector_type(2))) float;
using short8 = __attribute__((ext_vector_type(8))) short;
using u32x4  = __attribute__((ext_vector_type(4))) unsigned int;

constexpr int Cc  = 256;
constexpr int HWc = 3136;                 // 56*56
constexpr int CHW = Cc * HWc;             // 802816
constexpr float Mf = 200704.0f;           // 64*3136
constexpr int GX  = 196;                  // 3136 tiles / 196 = 16 tiles/block
constexpr int LDB = 72;                   // bf16 LDS row stride (144 B)

// workspace layout (float offsets)
constexpr int WS_SUM  = 0;                       // 256
constexpr int WS_G    = 256;                     // 4*4096
constexpr int WS_WM   = WS_G + 16384;            // 4*4096
constexpr int WS_BETA = WS_WM + 16384;           // 256
constexpr int WS_SLAB = WS_BETA + 256;           // 784 * 4096 partial Grams
constexpr int WS_SSUM = WS_SLAB + 784 * 4096;    // 784 * 64 partial channel sums

__device__ __forceinline__ unsigned cvtpk(float lo, float hi) {
    __hip_bfloat162 h = __float22bfloat162_rn(float2{lo, hi});
    unsigned u;
    __builtin_memcpy(&u, &h, 4);
    return u;
}

__device__ __forceinline__ unsigned short bf16rn(float v) {
    unsigned u = __builtin_bit_cast(unsigned, v);
    u += 0x7FFFu + ((u >> 16) & 1u);
    return (unsigned short)(u >> 16);
}
__device__ __forceinline__ float frombf(unsigned short h) {
    unsigned u = (unsigned)h << 16;
    return __builtin_bit_cast(float, u);
}

__device__ __forceinline__ f32x4v mfma16(short8 a, short8 b, f32x4v c) {
    return __builtin_amdgcn_mfma_f32_16x16x32_bf16(a, b, c, 0, 0, 0);
}

// ---------------------------------------------------------------------------
// Kernel 1: partial Gram. grid (196,4) x 256 (4 waves). LDS 36.9KB -> 4 blk/CU.
// ---------------------------------------------------------------------------
extern "C" __global__ __launch_bounds__(256, 4)
void k_gram(const float* __restrict__ X, float* __restrict__ ws) {
    __shared__ __align__(16) unsigned short tg[2][2][64 * LDB];
    const int g = blockIdx.y, bx = blockIdx.x, tid = threadIdx.x;
    const int lane = tid & 63, w = tid >> 6;
    const int row = tid >> 2, mo = (tid & 3) << 4;     // load mapping
    const int l15 = lane & 15, lg = lane >> 4;
    const int CBi0 = (w >> 1) << 1, CBj0 = (w & 1) << 1;
    const float* Xg = X + (size_t)g * 64 * HWc;

    f32x4v acc[2][2];
    #pragma unroll
    for (int i = 0; i < 2; ++i)
        #pragma unroll
        for (int j = 0; j < 2; ++j) acc[i][j] = (f32x4v){0.f, 0.f, 0.f, 0.f};
    float csum = 0.0f;

    f32x4v curA[4], curB[4];
    auto loadt = [&](int t, f32x4v* cur) {
        const int b = t / 49, hw0 = (t - b * 49) << 6;
        const float* p = Xg + (size_t)b * CHW + (size_t)row * HWc + hw0 + mo;
        cur[0] = *(const f32x4v*)(p);      cur[1] = *(const f32x4v*)(p + 4);
        cur[2] = *(const f32x4v*)(p + 8);  cur[3] = *(const f32x4v*)(p + 12);
    };
    auto packt = [&](const f32x4v* cur, unsigned short* dstbuf) {
        unsigned pk[8];
        #pragma unroll
        for (int i = 0; i < 4; ++i) {
            csum += (cur[i].x + cur[i].y) + (cur[i].z + cur[i].w);
            pk[2*i]   = cvtpk(cur[i].x, cur[i].y);
            pk[2*i+1] = cvtpk(cur[i].z, cur[i].w);
        }
        unsigned short* dst = dstbuf + row * LDB + mo;
        *(u32x4*)(dst)     = (u32x4){pk[0], pk[1], pk[2], pk[3]};
        *(u32x4*)(dst + 8) = (u32x4){pk[4], pk[5], pk[6], pk[7]};
    };
    auto comp = [&](const unsigned short* T) {
        #pragma unroll
        for (int s = 0; s < 2; ++s) {
            const int ko = 8 * lg + 32 * s;
            const short8 a0 = *(const short8*)&T[(CBi0 * 16      + l15) * LDB + ko];
            const short8 a1 = *(const short8*)&T[((CBi0+1) * 16  + l15) * LDB + ko];
            const short8 b0 = *(const short8*)&T[(CBj0 * 16      + l15) * LDB + ko];
            const short8 b1 = *(const short8*)&T[((CBj0+1) * 16  + l15) * LDB + ko];
            acc[0][0] = mfma16(a0, b0, acc[0][0]);
            acc[0][1] = mfma16(a0, b1, acc[0][1]);
            acc[1][0] = mfma16(a1, b0, acc[1][0]);
            acc[1][1] = mfma16(a1, b1, acc[1][1]);
        }
    };

    loadt(bx, curA);
    loadt(bx + GX, curB);

    int buf = 0;
    for (int kk = 0; kk < 8; ++kk) {
        packt(curA, tg[buf][0]);
        packt(curB, tg[buf][1]);
        __syncthreads();
        if (kk < 7) {                              // prefetch next 2 tiles
            loadt(bx + GX * (2*kk + 2), curA);
            loadt(bx + GX * (2*kk + 3), curB);
        }
        comp(tg[buf][0]);
        comp(tg[buf][1]);
        buf ^= 1;
    }

    csum += __shfl_down(csum, 1, 4);
    csum += __shfl_down(csum, 2, 4);
    if ((tid & 3) == 0)
        ws[WS_SSUM + (g * GX + bx) * 64 + row] = csum;

    float* Gp = ws + WS_SLAB + (size_t)(g * GX + bx) * 4096;
    #pragma unroll
    for (int ci = 0; ci < 2; ++ci)
        #pragma unroll
        for (int cj = 0; cj < 2; ++cj)
            #pragma unroll
            for (int reg = 0; reg < 4; ++reg) {
                const int r = (CBi0 + ci) * 16 + lg * 4 + reg;
                const int c = (CBj0 + cj) * 16 + l15;
                Gp[r * 64 + c] = acc[ci][cj][reg];
            }
}

// ---------------------------------------------------------------------------
// Kernel 1b: reduce slabs. grid (64,4) x 256: block sums 64 cells over 196
// slabs (4 quarters x 49, coalesced 256B rows), full-chip BW.
// ---------------------------------------------------------------------------
extern "C" __global__ __launch_bounds__(256)
void k_reduce(float* __restrict__ ws) {
    __shared__ float part[4][64];
    const int g = blockIdx.y, chunk = blockIdx.x, tid = threadIdx.x;
    const int c63 = tid & 63, q = tid >> 6;
    const float* p = ws + WS_SLAB + (size_t)g * GX * 4096
                   + (size_t)(q * 49) * 4096 + chunk * 64 + c63;
    float s = 0.f;
    #pragma unroll 7
    for (int i = 0; i < 49; ++i) { s += *p; p += 4096; }
    part[q][c63] = s;
    __syncthreads();
    if (tid < 64)
        ws[WS_G + g * 4096 + chunk * 64 + tid] =
            (part[0][tid] + part[1][tid]) + (part[2][tid] + part[3][tid]);

    if (chunk == 0 && tid < 64) {
        const float* qq = ws + WS_SSUM + (size_t)g * GX * 64 + tid;
        float a0 = 0.f, a1 = 0.f, a2 = 0.f, a3 = 0.f;
        #pragma unroll 7
        for (int s4 = 0; s4 < 49; ++s4) {
            a0 += qq[0];
            a1 += qq[64];
            a2 += qq[128];
            a3 += qq[192];
            qq += 256;
        }
        ws[WS_SUM + g * 64 + tid] = (a0 + a1) + (a2 + a3);
    }
}

// ---------------------------------------------------------------------------
// Kernel 2: Newton-Schulz via MFMA (hi/lo bf16 split). 4 blocks x 256.
// M0=Sigma_N; per iter: W=1.5I-0.5M; P<-P*W; M<-(M*W)*W (skip M on last).
// Per mm per wave: 8 a-frag reads (regs) -> barrier -> 24 MFMA (b inline)
// -> scattered hi/lo b16 writes -> barrier.
// ---------------------------------------------------------------------------
__device__ __forceinline__ void mm_bf(
    unsigned short* Ch, unsigned short* Cl,
    const unsigned short* Ah, const unsigned short* Al,
    const unsigned short* Bh, const unsigned short* Bl,
    int CBi0, int CBj0, int l15, int lg)
{
    short8 ah[2][2], al[2][2];
    #pragma unroll
    for (int ci = 0; ci < 2; ++ci)
        #pragma unroll
        for (int s = 0; s < 2; ++s) {
            const int off = ((CBi0 + ci) * 16 + l15) * LDB + 8 * lg + 32 * s;
            ah[ci][s] = *(const short8*)&Ah[off];
            al[ci][s] = *(const short8*)&Al[off];
        }
    __syncthreads();                    // all a-frags in regs before C(=A) written

    f32x4v acc[2][2];
    #pragma unroll
    for (int i = 0; i < 2; ++i)
        #pragma unroll
        for (int j = 0; j < 2; ++j) acc[i][j] = (f32x4v){0.f, 0.f, 0.f, 0.f};

    #pragma unroll
    for (int s = 0; s < 2; ++s) {
        short8 bh[2], bl[2];
        #pragma unroll
        for (int cj = 0; cj < 2; ++cj) {
            const int off = ((CBj0 + cj) * 16 + l15) * LDB + 8 * lg + 32 * s;
            bh[cj] = *(const short8*)&Bh[off];
            bl[cj] = *(const short8*)&Bl[off];
        }
        // term-major order: same-acc MFMAs are 4 apart (hides MFMA latency)
        #pragma unroll
        for (int ci = 0; ci < 2; ++ci)
            #pragma unroll
            for (int cj = 0; cj < 2; ++cj)
                acc[ci][cj] = mfma16(ah[ci][s], bh[cj], acc[ci][cj]);
        #pragma unroll
        for (int ci = 0; ci < 2; ++ci)
            #pragma unroll
            for (int cj = 0; cj < 2; ++cj)
                acc[ci][cj] = mfma16(al[ci][s], bh[cj], acc[ci][cj]);
        #pragma unroll
        for (int ci = 0; ci < 2; ++ci)
            #pragma unroll
            for (int cj = 0; cj < 2; ++cj)
                acc[ci][cj] = mfma16(ah[ci][s], bl[cj], acc[ci][cj]);
    }

    #pragma unroll
    for (int ci = 0; ci < 2; ++ci)
        #pragma unroll
        for (int cj = 0; cj < 2; ++cj)
            #pragma unroll
            for (int reg = 0; reg < 4; ++reg) {
                const int row = (CBi0 + ci) * 16 + lg * 4 + reg;
                const int col = (CBj0 + cj) * 16 + l15;
                const float c = acc[ci][cj][reg];
                const unsigned short h = bf16rn(c);
                Ch[row * LDB + col] = h;
                Cl[row * LDB + col] = bf16rn(c - frombf(h));
            }
    __syncthreads();
}

extern "C" __global__ __launch_bounds__(256)
void k_solve(const float* __restrict__ weight, const float* __restrict__ bias,
             float* __restrict__ ws) {
    __shared__ __align__(16) unsigned short Mh[64 * LDB], Ml[64 * LDB];
    __shared__ __align__(16) unsigned short Ph[64 * LDB], Pl[64 * LDB];
    __shared__ __align__(16) unsigned short Wh[64 * LDB], Wl[64 * LDB];
    __shared__ __align__(16) unsigned short Th[64 * LDB], Tl[64 * LDB];
    __shared__ float mean_s[64];
    __shared__ float diag_s[64];
    __shared__ float red;

    const int g = blockIdx.x, tid = threadIdx.x;
    const int lane = tid & 63, w = tid >> 6;
    const int l15 = lane & 15, lg = lane >> 4;
    const int CBi0 = (w >> 1) << 1, CBj0 = (w & 1) << 1;
    const int r = tid >> 2, ch = (tid & 3) << 4;   // elementwise: row r, 16 cols

    if (tid < 64) mean_s[tid] = ws[WS_SUM + g * 64 + tid] * (1.0f / Mf);
    __syncthreads();

    // Sigma fp32 in regs; stash diagonal for trace
    const float* Gp = ws + WS_G + g * 4096;
    const float mr = mean_s[r];
    f32x4v sv[4];
    #pragma unroll
    for (int j4 = 0; j4 < 4; ++j4) {
        const int c = ch + 4 * j4;
        const f32x4v gv = *(const f32x4v*)&Gp[r * 64 + c];
        const f32x4v mc = *(const f32x4v*)&mean_s[c];
        #pragma unroll
        for (int j = 0; j < 4; ++j) {
            float v = gv[j] * (1.0f / Mf) - mr * mc[j];
            if (c + j == r) { v += EPS_F; diag_s[r] = v; }
            sv[j4][j] = v;
        }
    }
    __syncthreads();
    if (tid == 0) {
        float tr = 0.f;
        #pragma unroll
        for (int i = 0; i < 64; ++i) tr += diag_s[i];
        red = 1.0f / tr;
    }
    __syncthreads();
    const float rtr = red;

    // M = Sigma * rtr (hi/lo); P = I
    #pragma unroll
    for (int j4 = 0; j4 < 4; ++j4) {
        #pragma unroll
        for (int j = 0; j < 4; ++j) {
            const int c = ch + 4 * j4 + j;
            const float v = sv[j4][j] * rtr;
            const unsigned short h = bf16rn(v);
            Mh[r * LDB + c] = h;
            Ml[r * LDB + c] = bf16rn(v - frombf(h));
            Ph[r * LDB + c] = (c == r) ? (unsigned short)0x3F80 : (unsigned short)0;
            Pl[r * LDB + c] = 0;
        }
    }
    __syncthreads();

    for (int t = 0; t < 5; ++t) {
        // W = 1.5I - 0.5M (elementwise, reconstruct fp32 then re-split)
        #pragma unroll
        for (int j16 = 0; j16 < 16; ++j16) {
            const int c = ch + j16;
            const float m = frombf(Mh[r * LDB + c]) + frombf(Ml[r * LDB + c]);
            const float wv = ((c == r) ? 1.5f : 0.0f) - 0.5f * m;
            const unsigned short h = bf16rn(wv);
            Wh[r * LDB + c] = h;
            Wl[r * LDB + c] = bf16rn(wv - frombf(h));
        }
        __syncthreads();
        mm_bf(Ph, Pl, Ph, Pl, Wh, Wl, CBi0, CBj0, l15, lg);      // P <- P*W
        if (t < 4) {
            mm_bf(Th, Tl, Mh, Ml, Wh, Wl, CBi0, CBj0, l15, lg);  // T = M*W
            mm_bf(Mh, Ml, Th, Tl, Wh, Wl, CBi0, CBj0, l15, lg);  // M = T*W
        }
    }

    // fold weight/bias/mean
    const float srtr = sqrtf(rtr);
    const float wr = weight[g * 64 + r];
    float* Wp = ws + WS_WM + g * 4096;
    float part = 0.0f;
    #pragma unroll
    for (int j16 = 0; j16 < 16; ++j16) {
        const int c = ch + j16;
        const float p = frombf(Ph[r * LDB + c]) + frombf(Pl[r * LDB + c]);
        const float wm = p * srtr;
        Wp[r * 64 + c] = wm * wr;
        part += wm * mean_s[c];
    }
    part += __shfl_down(part, 1, 4);
    part += __shfl_down(part, 2, 4);
    if ((tid & 3) == 0)
        ws[WS_BETA + g * 64 + r] = bias[g * 64 + r] - wr * part;
}

// ---------------------------------------------------------------------------
// Kernel 3: apply. grid (196,4) x 256. wm staged into tx[0][0] (aliased).
// NT stores keep the 205MB out stream out of L3.
// ---------------------------------------------------------------------------
extern "C" __global__ __launch_bounds__(256, 4)
void k_apply(const float* __restrict__ X, const float* __restrict__ ws,
             float* __restrict__ out) {
    __shared__ __align__(16) unsigned short tx[2][2][64 * LDB];
    __shared__ __align__(16) float beta_sh[64];

    const int g = blockIdx.y, bx = blockIdx.x, tid = threadIdx.x;
    const int lane = tid & 63, w = tid >> 6;
    const int l15 = lane & 15, lg = lane >> 4;
    const float* Xg = X + (size_t)g * 64 * HWc;

    {   // stage wm fp32 -> bf16 into tx[0][0] (reused as x-tile later)
        unsigned short* wm_s = &tx[0][0][0];
        const float* Wp = ws + WS_WM + g * 4096;
        const int r = tid >> 2, chh = (tid & 3) << 4;
        const float* p = Wp + r * 64 + chh;
        const f32x4v v0 = *(const f32x4v*)(p);      const f32x4v v1 = *(const f32x4v*)(p + 4);
        const f32x4v v2 = *(const f32x4v*)(p + 8);  const f32x4v v3 = *(const f32x4v*)(p + 12);
        unsigned short* dst = &wm_s[r * LDB + chh];
        *(u32x4*)(dst)     = (u32x4){cvtpk(v0.x,v0.y), cvtpk(v0.z,v0.w),
                                     cvtpk(v1.x,v1.y), cvtpk(v1.z,v1.w)};
        *(u32x4*)(dst + 8) = (u32x4){cvtpk(v2.x,v2.y), cvtpk(v2.z,v2.w),
                                     cvtpk(v3.x,v3.y), cvtpk(v3.z,v3.w)};
        if (tid < 64) beta_sh[tid] = ws[WS_BETA + g * 64 + tid];
    }
    __syncthreads();

    const int CB0 = (w >> 1) << 1, MB0 = (w & 1) << 1;
    short8 afrag[2][2];
    {
        const unsigned short* wm_s = &tx[0][0][0];
        #pragma unroll
        for (int ci = 0; ci < 2; ++ci)
            #pragma unroll
            for (int s = 0; s < 2; ++s)
                afrag[ci][s] = *(const short8*)&wm_s[((CB0 + ci) * 16 + l15) * LDB + 8 * lg + 32 * s];
    }

    float betav[2][4]; int crow[2][4];
    #pragma unroll
    for (int ci = 0; ci < 2; ++ci)
        #pragma unroll
        for (int reg = 0; reg < 4; ++reg) {
            const int cl = (CB0 + ci) * 16 + lg * 4 + reg;
            betav[ci][reg] = beta_sh[cl];
            crow[ci][reg]  = (g * 64 + cl) * HWc;
        }
    __syncthreads();   // frag/beta reads done before tx[0][0] is overwritten

    const int rT   = 32 * (lane >> 5) + 16 * (lane & 1) + ((lane & 31) >> 1);
    const int mcb  = 32 * (w & 1) + 2 * l15;            // store col base
    const int e0 = w * 16;

    float curA[16], curB[16];
    auto loadt = [&](int t, float* cur) {
        const int b = t / 49, hw0 = (t - b * 49) << 6;
        const float* p = Xg + (size_t)b * CHW + (size_t)e0 * HWc + hw0 + lane;
        #pragma unroll
        for (int j = 0; j < 16; ++j) cur[j] = p[(size_t)j * HWc];
    };
    auto packt = [&](const float* cur, unsigned short* dstbuf) {
        unsigned short* dst = dstbuf + rT * LDB + e0;
        *(u32x4*)(dst)     = (u32x4){cvtpk(cur[0],cur[1]),   cvtpk(cur[2],cur[3]),
                                     cvtpk(cur[4],cur[5]),   cvtpk(cur[6],cur[7])};
        *(u32x4*)(dst + 8) = (u32x4){cvtpk(cur[8],cur[9]),   cvtpk(cur[10],cur[11]),
                                     cvtpk(cur[12],cur[13]), cvtpk(cur[14],cur[15])};
    };
    auto compst = [&](const unsigned short* T, int t) {
        f32x4v acc[2][2];
        #pragma unroll
        for (int i = 0; i < 2; ++i)
            #pragma unroll
            for (int j = 0; j < 2; ++j) acc[i][j] = (f32x4v){0.f,0.f,0.f,0.f};
        #pragma unroll
        for (int s = 0; s < 2; ++s) {
            const int ko = 8 * lg + 32 * s;
            const short8 b0 = *(const short8*)&T[(MB0 * 16     + l15) * LDB + ko];
            const short8 b1 = *(const short8*)&T[((MB0+1) * 16 + l15) * LDB + ko];
            acc[0][0] = mfma16(afrag[0][s], b0, acc[0][0]);
            acc[0][1] = mfma16(afrag[0][s], b1, acc[0][1]);
            acc[1][0] = mfma16(afrag[1][s], b0, acc[1][0]);
            acc[1][1] = mfma16(afrag[1][s], b1, acc[1][1]);
        }
        const int b = t / 49, hw0 = (t - b * 49) << 6;
        float* ob = out + (size_t)b * CHW + hw0 + mcb;
        #pragma unroll
        for (int ci = 0; ci < 2; ++ci)
            #pragma unroll
            for (int reg = 0; reg < 4; ++reg) {
                const float bt = betav[ci][reg];
                const f32x2v v = {acc[ci][0][reg] + bt, acc[ci][1][reg] + bt};
                __builtin_nontemporal_store(v, (f32x2v*)(ob + crow[ci][reg]));
            }
    };

    loadt(bx, curA);
    loadt(bx + GX, curB);

    int buf = 0;
    for (int kk = 0; kk < 8; ++kk) {
        packt(curA, tx[buf][0]);
        packt(curB, tx[buf][1]);
        __syncthreads();
        if (kk < 7) {
            loadt(bx + GX * (2*kk + 2), curA);
            loadt(bx + GX * (2*kk + 3), curB);
        }
        compst(tx[buf][0], bx + GX * (2*kk));
        compst(tx[buf][1], bx + GX * (2*kk + 1));
        buf ^= 1;
    }
}

// ---------------------------------------------------------------------------
extern "C" void kernel_launch(void* const* d_in, const int* in_sizes, int n_in,
                              void* d_out, int out_size, void* d_ws, size_t ws_size,
                              hipStream_t stream) {
    const float* X      = (const float*)d_in[0];
    const float* weight = (const float*)d_in[1];
    const float* bias   = (const float*)d_in[2];
    float* out = (float*)d_out;
    float* ws  = (float*)d_ws;

    hipLaunchKernelGGL(k_gram,   dim3(GX, 4), dim3(256), 0, stream, X, ws);
    hipLaunchKernelGGL(k_reduce, dim3(64, 4), dim3(256), 0, stream, ws);
    hipLaunchKernelGGL(k_solve,  dim3(4),     dim3(256), 0, stream, weight, bias, ws);
    hipLaunchKernelGGL(k_apply,  dim3(GX, 4), dim3(256), 0, stream, X, ws, out);
}